// Round 6
// baseline (201.437 us; speedup 1.0000x reference)
//
#include <hip/hip_runtime.h>
#include <math.h>

#define BB 16
#define SS 256
#define CC 17
#define NCH 16
#define DD 32
#define DFFN 64
#define HH 4
#define DH 8
#define EE 4

// ws layout (4-byte units):
//  [16 ..143]  K0[e][d]   [144..271] V0[e][d]
//  [512..66047]  XNS[b][s][n]
//  ints at WS_SPI: SP[b][p] (4096), OFF[b][e] (64)
//  WS_Q:   q fp32, prescaled by 1/sqrt(8)*log2(e)   [(b,p,n)][hh][8]
//  WS_KVU: k/v packed f16 as uints: [(b,n)][p][hh][k:4u v:4u]
#define WS_K0 16
#define WS_V0 144
#define WS_XNS 512
#define WS_SPI (WS_XNS + BB*SS*NCH)          // 66048
#define WS_Q   (WS_SPI + BB*SS + 64)         // 70208 (16B aligned)
#define WS_KVU (WS_Q + BB*SS*NCH*DD)         // 2167360

#define PRE 0.51006977f   // (1/sqrt(8)) * log2(e)

typedef __fp16 hv2 __attribute__((ext_vector_type(2)));

__device__ __forceinline__ unsigned pkh2(float a, float b) {
  hv2 r = __builtin_amdgcn_cvt_pkrtz(a, b);
  unsigned u; __builtin_memcpy(&u, &r, 4);
  return u;
}
__device__ __forceinline__ float fd2(unsigned a, unsigned b, float c) {
  hv2 av, bv;
  __builtin_memcpy(&av, &a, 4);
  __builtin_memcpy(&bv, &b, 4);
  return __builtin_amdgcn_fdot2(av, bv, c, false);
}
__device__ __forceinline__ float h2lo(unsigned u) {
  hv2 v; __builtin_memcpy(&v, &u, 4); return (float)v[0];
}
__device__ __forceinline__ float h2hi(unsigned u) {
  hv2 v; __builtin_memcpy(&v, &u, 4); return (float)v[1];
}

// ---------------------------------------------------------------------------
// Kernel 1: fused decomp (blocks 0..255) + prep (blocks 256..271), 256 thr.
// ---------------------------------------------------------------------------
__global__ void decomp_prep_kernel(const float* __restrict__ x,
                                   const float* __restrict__ ox,
                                   const float* __restrict__ sb,
                                   const float* __restrict__ g1,
                                   const float* __restrict__ bb1,
                                   const float* __restrict__ Wk,
                                   const float* __restrict__ Wv,
                                   float* __restrict__ ws) {
  const int t = threadIdx.x;  // 256
  if (blockIdx.x < 256) {
    // ---------------- decomposition ----------------
    const int b = blockIdx.x / NCH;
    const int c = blockIdx.x % NCH;
    __shared__ float xs[SS];
    __shared__ float pr[256], pi[256];
    __shared__ float amp[129];
    __shared__ float2 YY[129];
    __shared__ float sth;
    xs[t] = x[(b*SS + t)*CC + c];
    __syncthreads();
    const float TH0 = 0.024543692606170259f;  // 2*pi/256
    {
      const int f = (t & 127) + 1;
      const int half = t >> 7;
      float s1, c1; sincosf(TH0*(float)f, &s1, &c1);
      const int ph0 = (f * half * 128) & 255;
      float cr, si; sincosf(TH0*(float)ph0, &si, &cr);
      float xr = 0.f, xi = 0.f;
      for (int s2 = 0; s2 < 128; ++s2) {
        float xvv = xs[half*128 + s2];
        xr += xvv * cr;
        xi -= xvv * si;
        float nc = cr*c1 - si*s1;
        si = si*c1 + cr*s1;
        cr = nc;
      }
      pr[t] = xr; pi[t] = xi;
    }
    __syncthreads();
    if (t < 128) {
      float xr = pr[t] + pr[t+128];
      float xi = pi[t] + pi[t+128];
      pr[t] = xr; pi[t] = xi;
      amp[t+1] = sqrtf(xr*xr + xi*xi);
    }
    __syncthreads();
    if (t < 64) {
      float a0 = amp[t+1], a1 = amp[t+65];
      int i0 = t+1, i1 = t+65;
      float th = -1e30f;
      for (int r = 0; r < 4; ++r) {
        float mv = (a0 > a1) ? a0 : a1;
        int   mi = (a0 > a1) ? i0 : i1;
        for (int off = 32; off > 0; off >>= 1) {
          float ov = __shfl_xor(mv, off);
          int   oi = __shfl_xor(mi, off);
          if (ov > mv || (ov == mv && oi < mi)) { mv = ov; mi = oi; }
        }
        th = mv;
        if (mi == i0) a0 = -1e30f;
        if (mi == i1) a1 = -1e30f;
      }
      if (t == 0) sth = th;
    }
    __syncthreads();
    if (t < 128) {
      const int f = t + 1;
      float wgt = (amp[f] >= sth) ? ((f == 128) ? 1.0f : 2.0f) * (1.0f/256.0f) : 0.0f;
      YY[f] = make_float2(wgt * pr[t], wgt * pi[t]);
    }
    __syncthreads();
    float s1, c1; sincosf(TH0*(float)t, &s1, &c1);
    float cr = c1, si = s1, acc = 0.f;
    for (int f = 1; f <= 128; ++f) {
      float2 y = YY[f];
      acc += y.x*cr - y.y*si;
      float nc = cr*c1 - si*s1;
      si = si*c1 + cr*s1;
      cr = nc;
    }
    const float season = acc;
    float s4 = 0.f, s8 = 0.f, s12 = 0.f;
    #pragma unroll
    for (int j = 0; j < 4; ++j)  { int p = t + j - 1; p = p < 0 ? 0 : (p > SS-1 ? SS-1 : p); s4  += xs[p]; }
    #pragma unroll
    for (int j = 0; j < 8; ++j)  { int p = t + j - 3; p = p < 0 ? 0 : (p > SS-1 ? SS-1 : p); s8  += xs[p]; }
    #pragma unroll
    for (int j = 0; j < 12; ++j) { int p = t + j - 5; p = p < 0 ? 0 : (p > SS-1 ? SS-1 : p); s12 += xs[p]; }
    float trend = (s4 * 0.25f + s8 * 0.125f + s12 * (1.0f/12.0f)) * (1.0f/3.0f);
    ws[WS_XNS + (b*SS + t)*NCH + c] = xs[t] + season + trend;
  } else {
    // ---------------- prep ----------------
    const int b = blockIdx.x - 256;
    __shared__ float red[8];
    __shared__ int asg[SS];
    __shared__ int cnt[EE];
    __shared__ float z0[EE*DD];
    float mn = 3e38f, mx = -3e38f;
    for (int i = t; i < BB*SS; i += 256) {
      float v = ox[2*i + 1];
      mn = fminf(mn, v); mx = fmaxf(mx, v);
    }
    for (int off = 32; off > 0; off >>= 1) {
      mn = fminf(mn, __shfl_xor(mn, off));
      mx = fmaxf(mx, __shfl_xor(mx, off));
    }
    if ((t & 63) == 0) { red[(t>>6)*2] = mn; red[(t>>6)*2+1] = mx; }
    __syncthreads();
    mn = fminf(fminf(red[0], red[2]), fminf(red[4], red[6]));
    mx = fmaxf(fmaxf(red[1], red[3]), fmaxf(red[5], red[7]));
    const float step = (mx - mn) * 0.25f;
    const float e1 = mn + step, e2 = mn + 2.f*step, e3 = mn + 3.f*step;
    float sc = ox[(b*SS + t)*2 + 1];
    asg[t] = (sc >= e1) + (sc >= e2) + (sc >= e3);
    __syncthreads();
    if (t < EE) {
      int c = 0;
      for (int s2 = 0; s2 < SS; ++s2) c += (asg[s2] == t);
      cnt[t] = c;
    }
    __syncthreads();
    int* SPw  = (int*)ws + WS_SPI;
    int* OFFw = SPw + BB*SS;
    if (t < EE) {
      int off = 0;
      for (int i = 0; i < t; ++i) off += cnt[i];
      OFFw[b*EE + t] = off;
      int kp = off;
      for (int s2 = 0; s2 < SS; ++s2) if (asg[s2] == t) SPw[b*SS + (kp++)] = s2;
    }
    if (t < 128) {
      int ee = t >> 5, d = t & 31;
      float m = 0.f;
      for (int i = 0; i < DD; ++i) m += sb[i];
      m *= (1.0f/DD);
      float var = 0.f;
      for (int i = 0; i < DD; ++i) { float df = sb[i]-m; var += df*df; }
      var *= (1.0f/DD);
      float rs = rsqrtf(var + 1e-5f);
      z0[ee*DD + d] = (sb[d]-m)*rs*g1[ee*DD+d] + bb1[ee*DD+d];
    }
    __syncthreads();
    if (b == 0 && t < 128) {
      int ee = t >> 5, d = t & 31;
      float k0 = 0.f, v0 = 0.f;
      for (int i = 0; i < DD; ++i) {
        float zz = z0[ee*DD + i];
        k0 += zz * Wk[ee*DD*DD + i*DD + d];
        v0 += zz * Wv[ee*DD*DD + i*DD + d];
      }
      ws[WS_K0 + ee*DD + d] = k0;
      ws[WS_V0 + ee*DD + d] = v0;
    }
  }
}

// ---------------------------------------------------------------------------
// Kernel 2: qkv via fdot2 against transposed f16 weights in LDS (24 KB).
// ---------------------------------------------------------------------------
__launch_bounds__(256, 4)
__global__ void qkv_kernel(float* __restrict__ ws,
    const float* __restrict__ Wq, const float* __restrict__ Wk,
    const float* __restrict__ Wv,
    const float* __restrict__ g1, const float* __restrict__ bb1,
    const float* __restrict__ sW, const float* __restrict__ sb) {
  __shared__ unsigned wT[6144];  // WqT [0,2048) WkT [2048,4096) WvT [4096,6144)
                                 // layout: base + (e*32 + d)*16 + ip, pairs along i
  const int t = threadIdx.x;
  #pragma unroll
  for (int it = 0; it < 24; ++it) {
    int idx = it*256 + t;
    int mat = idx >> 11;
    int r = idx & 2047;
    int ed = r >> 4, ip = r & 15;
    int e = ed >> 5, d = ed & 31;
    const float* Wm = (mat == 0) ? Wq : (mat == 1) ? Wk : Wv;
    const float* base = Wm + e*1024 + d;
    wT[idx] = pkh2(base[(2*ip)*32], base[(2*ip+1)*32]);
  }
  const int gI = blockIdx.x*256 + t;
  const int hh = gI & 3;
  const int pos = gI >> 2;               // (b,p,n)
  const int n = pos & 15;
  const int p = (pos >> 4) & 255;
  const int b = pos >> 12;
  const int* SP  = (const int*)ws + WS_SPI;
  const int* OFF = SP + BB*SS;
  const int o1 = OFF[b*4+1], o2 = OFF[b*4+2], o3 = OFF[b*4+3];
  const int e = (p >= o1) + (p >= o2) + (p >= o3);
  const int s = SP[b*SS + p];
  const float xv = ws[WS_XNS + (b*SS + s)*NCH + n];

  float h[DD];
  #pragma unroll
  for (int d = 0; d < DD; ++d) h[d] = xv * sW[d] + sb[d];
  float m = 0.f;
  #pragma unroll
  for (int d = 0; d < DD; ++d) m += h[d];
  m *= (1.0f/DD);
  float var = 0.f;
  #pragma unroll
  for (int d = 0; d < DD; ++d) { float df = h[d]-m; var += df*df; }
  var *= (1.0f/DD);
  float rs = rsqrtf(var + 1e-5f);
  unsigned zp[16];
  #pragma unroll
  for (int ip = 0; ip < 16; ++ip) {
    float za = (h[2*ip]  -m)*rs*g1[e*DD+2*ip]   + bb1[e*DD+2*ip];
    float zb = (h[2*ip+1]-m)*rs*g1[e*DD+2*ip+1] + bb1[e*DD+2*ip+1];
    zp[ip] = pkh2(za, zb);
  }
  __syncthreads();

  float q[DH], kk[DH], vv[DH];
  #pragma unroll
  for (int dd = 0; dd < DH; ++dd) {
    int d = hh*DH + dd;
    const uint4* rq = (const uint4*)&wT[(e*32 + d)*16];
    const uint4* rk = (const uint4*)&wT[2048 + (e*32 + d)*16];
    const uint4* rv = (const uint4*)&wT[4096 + (e*32 + d)*16];
    float aq = 0.f, ak = 0.f, av = 0.f;
    #pragma unroll
    for (int g4 = 0; g4 < 4; ++g4) {
      uint4 wq4 = rq[g4], wk4 = rk[g4], wv4 = rv[g4];
      aq = fd2(zp[4*g4+0], wq4.x, aq); aq = fd2(zp[4*g4+1], wq4.y, aq);
      aq = fd2(zp[4*g4+2], wq4.z, aq); aq = fd2(zp[4*g4+3], wq4.w, aq);
      ak = fd2(zp[4*g4+0], wk4.x, ak); ak = fd2(zp[4*g4+1], wk4.y, ak);
      ak = fd2(zp[4*g4+2], wk4.z, ak); ak = fd2(zp[4*g4+3], wk4.w, ak);
      av = fd2(zp[4*g4+0], wv4.x, av); av = fd2(zp[4*g4+1], wv4.y, av);
      av = fd2(zp[4*g4+2], wv4.z, av); av = fd2(zp[4*g4+3], wv4.w, av);
    }
    q[dd] = aq; kk[dd] = ak; vv[dd] = av;
  }
  float* qp = ws + WS_Q + pos*32 + hh*DH;
  ((float4*)qp)[0] = make_float4(q[0]*PRE, q[1]*PRE, q[2]*PRE, q[3]*PRE);
  ((float4*)qp)[1] = make_float4(q[4]*PRE, q[5]*PRE, q[6]*PRE, q[7]*PRE);
  unsigned* kvg = (unsigned*)ws + WS_KVU + ((b*NCH + n)*SS + p)*32 + hh*8;
  ((uint4*)kvg)[0] = make_uint4(pkh2(kk[0],kk[1]), pkh2(kk[2],kk[3]), pkh2(kk[4],kk[5]), pkh2(kk[6],kk[7]));
  ((uint4*)kvg)[1] = make_uint4(pkh2(vv[0],vv[1]), pkh2(vv[2],vv[3]), pkh2(vv[4],vv[5]), pkh2(vv[6],vv[7]));
}

// ---------------------------------------------------------------------------
// Kernel 3: attn + Wo + FFN via fdot2. Grid (b,n,half)=512 x 512 thr.
// kv 32 KB + transposed f16 weights 40 KB = 72 KB -> 2 blocks/CU.
// ---------------------------------------------------------------------------
__launch_bounds__(512, 4)
__global__ void attn_ffn_kernel(const float* __restrict__ ws,
    const float* __restrict__ sW, const float* __restrict__ sb,
    const float* __restrict__ Wo,
    const float* __restrict__ g2, const float* __restrict__ bb2,
    const float* __restrict__ W1, const float* __restrict__ b1,
    const float* __restrict__ W2, const float* __restrict__ b2,
    float* __restrict__ out) {
  const int blk = blockIdx.x;
  const int hq = blk & 1;
  const int n = (blk >> 1) & 15;
  const int b = blk >> 5;
  const int t = threadIdx.x;
  const int wj = t >> 6;        // wave 0..7
  const int lane = t & 63;
  const int pg = lane >> 2;     // 0..15
  const int hh = lane & 3;
  const int g = hq + 2*wj;      // sorted group, strided for balance
  const int p = g*16 + pg;
  const int pb = wj*16 + pg;    // 0..127 local scratch index
  __shared__ unsigned lds[8192];     // kv; scratch aliases after attention
  __shared__ unsigned wl[10240];     // WoT [0,2048) W1T [2048,6144) W2T [6144,10240)
  float* fl = (float*)lds;

  // stage kv
  const unsigned* src = (const unsigned*)ws + WS_KVU + (b*NCH + n)*8192;
  #pragma unroll
  for (int i = 0; i < 4; ++i) {
    int idx = (i*512 + t)*4;
    *(uint4*)&lds[idx] = *(const uint4*)&src[idx];
  }
  // stage transposed f16 weights
  #pragma unroll
  for (int it = 0; it < 20; ++it) {
    int idx = it*512 + t;
    unsigned val;
    if (idx < 2048) {              // WoT: (e*32+d)*16 + ip
      int ed = idx >> 4, ip = idx & 15;
      int e2 = ed >> 5, d = ed & 31;
      const float* base = Wo + e2*1024 + d;
      val = pkh2(base[(2*ip)*32], base[(2*ip+1)*32]);
    } else if (idx < 6144) {       // W1T: (e*64+j)*16 + ip
      int r = idx - 2048;
      int ej = r >> 4, ip = r & 15;
      int e2 = ej >> 6, j = ej & 63;
      const float* base = W1 + e2*2048 + j;
      val = pkh2(base[(2*ip)*64], base[(2*ip+1)*64]);
    } else {                       // W2T: (e*32+d)*32 + jp
      int r = idx - 6144;
      int edd = r >> 5, jp = r & 31;
      int e2 = edd >> 5, d = edd & 31;
      const float* base = W2 + e2*2048 + d;
      val = pkh2(base[(2*jp)*32], base[(2*jp+1)*32]);
    }
    wl[idx] = val;
  }

  const int* SP  = (const int*)ws + WS_SPI;
  const int* OFF = SP + BB*SS;
  const int o1 = OFF[b*4+1], o2 = OFF[b*4+2], o3 = OFF[b*4+3];
  const int e = (p >= o1) + (p >= o2) + (p >= o3);
  const int beg = (e==0) ? 0  : ((e==1) ? o1 : ((e==2) ? o2 : o3));
  const int end = (e==0) ? o1 : ((e==1) ? o2 : ((e==2) ? o3 : SS));
  const int s = SP[b*SS + p];

  float qf[DH];
  {
    const float* qp = ws + WS_Q + ((b*SS + p)*NCH + n)*32 + hh*DH;
    float4 qa = ((const float4*)qp)[0];
    float4 qb = ((const float4*)qp)[1];
    qf[0]=qa.x; qf[1]=qa.y; qf[2]=qa.z; qf[3]=qa.w;
    qf[4]=qb.x; qf[5]=qb.y; qf[6]=qb.z; qf[7]=qb.w;
  }
  unsigned qp2[4];
  #pragma unroll
  for (int i = 0; i < 4; ++i) qp2[i] = pkh2(qf[2*i], qf[2*i+1]);
  float s0 = 0.f;
  #pragma unroll
  for (int d = 0; d < DH; ++d) s0 += qf[d] * ws[WS_K0 + e*DD + hh*DH + d];
  float v0s[DH];
  #pragma unroll
  for (int d = 0; d < DH; ++d) v0s[d] = ws[WS_V0 + e*DD + hh*DH + d];
  __syncthreads();   // kv + weights staged

  float wsum = 0.f;
  float o[DH] = {0,0,0,0,0,0,0,0};
  for (int jk = beg; jk < end; ++jk) {
    uint4 ku = *(const uint4*)&lds[jk*32 + hh*8];
    uint4 vu = *(const uint4*)&lds[jk*32 + hh*8 + 4];
    float a = 0.f;
    a = fd2(qp2[0], ku.x, a); a = fd2(qp2[1], ku.y, a);
    a = fd2(qp2[2], ku.z, a); a = fd2(qp2[3], ku.w, a);
    float w = __builtin_amdgcn_exp2f(a);
    wsum += w;
    o[0] += w*h2lo(vu.x); o[1] += w*h2hi(vu.x);
    o[2] += w*h2lo(vu.y); o[3] += w*h2hi(vu.y);
    o[4] += w*h2lo(vu.z); o[5] += w*h2hi(vu.z);
    o[6] += w*h2lo(vu.w); o[7] += w*h2hi(vu.w);
  }
  const int nmis = SS - (end - beg);
  float w0 = (float)nmis * __builtin_amdgcn_exp2f(s0);
  wsum += w0;
  #pragma unroll
  for (int d = 0; d < DH; ++d) o[d] += w0 * v0s[d];
  float inv = 1.0f / wsum;
  #pragma unroll
  for (int d = 0; d < DH; ++d) o[d] *= inv;
  __syncthreads();   // all kv reads done; scratch may overwrite

  // o exchange (fp32, stride 33)
  #pragma unroll
  for (int d = 0; d < DH; ++d) fl[pb*33 + hh*DH + d] = o[d];
  __syncthreads();
  unsigned ovp[16];
  #pragma unroll
  for (int ip = 0; ip < 16; ++ip) ovp[ip] = pkh2(fl[pb*33 + 2*ip], fl[pb*33 + 2*ip+1]);

  // Wo + residual
  const float xv = ws[WS_XNS + (b*SS + s)*NCH + n];
  float acc[DH];
  #pragma unroll
  for (int dd = 0; dd < DH; ++dd) {
    int d = hh*DH + dd;
    const uint4* row = (const uint4*)&wl[(e*32 + d)*16];
    float a = xv * sW[d] + sb[d];
    #pragma unroll
    for (int g4 = 0; g4 < 4; ++g4) {
      uint4 w4 = row[g4];
      a = fd2(ovp[4*g4+0], w4.x, a); a = fd2(ovp[4*g4+1], w4.y, a);
      a = fd2(ovp[4*g4+2], w4.z, a); a = fd2(ovp[4*g4+3], w4.w, a);
    }
    acc[dd] = a;
  }
  __syncthreads();   // o reads done; reuse region for h2
  #pragma unroll
  for (int dd = 0; dd < DH; ++dd) fl[pb*33 + hh*DH + dd] = acc[dd];
  __syncthreads();

  float h2r[DD];
  #pragma unroll
  for (int i = 0; i < DD; ++i) h2r[i] = fl[pb*33 + i];
  float m = 0.f;
  #pragma unroll
  for (int d = 0; d < DD; ++d) m += h2r[d];
  m *= (1.0f/DD);
  float var = 0.f;
  #pragma unroll
  for (int d = 0; d < DD; ++d) { float df = h2r[d]-m; var += df*df; }
  var *= (1.0f/DD);
  float rs = rsqrtf(var + 1e-5f);
  unsigned zp2[16];
  #pragma unroll
  for (int ip = 0; ip < 16; ++ip) {
    float za = (h2r[2*ip]  -m)*rs*g2[e*DD+2*ip]   + bb2[e*DD+2*ip];
    float zb = (h2r[2*ip+1]-m)*rs*g2[e*DD+2*ip+1] + bb2[e*DD+2*ip+1];
    zp2[ip] = pkh2(za, zb);
  }
  float hres[DH];
  #pragma unroll
  for (int dd = 0; dd < DH; ++dd) hres[dd] = h2r[hh*DH + dd];
  __syncthreads();   // h2 reads done; reuse region for f

  // FFN1: f[hh*16 .. +16)
  float f[16];
  #pragma unroll
  for (int jj = 0; jj < 16; ++jj) {
    int j = hh*16 + jj;
    const uint4* row = (const uint4*)&wl[2048 + (e*64 + j)*16];
    float a = b1[e*DFFN + j];
    #pragma unroll
    for (int g4 = 0; g4 < 4; ++g4) {
      uint4 w4 = row[g4];
      a = fd2(zp2[4*g4+0], w4.x, a); a = fd2(zp2[4*g4+1], w4.y, a);
      a = fd2(zp2[4*g4+2], w4.z, a); a = fd2(zp2[4*g4+3], w4.w, a);
    }
    f[jj] = fmaxf(a, 0.0f);
  }
  // f exchange as f16 pairs, stride 36 uints (16B-aligned rows)
  #pragma unroll
  for (int a2 = 0; a2 < 8; ++a2)
    lds[pb*36 + hh*8 + a2] = pkh2(f[2*a2], f[2*a2+1]);
  __syncthreads();

  // FFN2 + residual + b2
  uint4 fpr[8];
  #pragma unroll
  for (int g4 = 0; g4 < 8; ++g4) fpr[g4] = *(const uint4*)&lds[pb*36 + 4*g4];
  float acc2[DH];
  #pragma unroll
  for (int dd = 0; dd < DH; ++dd) {
    int d = hh*DH + dd;
    const uint4* row = (const uint4*)&wl[6144 + (e*32 + d)*32];
    float a = hres[dd] + b2[e*DD + d];
    #pragma unroll
    for (int g4 = 0; g4 < 8; ++g4) {
      uint4 w4 = row[g4];
      uint4 fq = fpr[g4];
      a = fd2(fq.x, w4.x, a); a = fd2(fq.y, w4.y, a);
      a = fd2(fq.z, w4.z, a); a = fd2(fq.w, w4.w, a);
    }
    acc2[dd] = a;
  }
  float* op = out + ((size_t)((b*SS + s)*NCH + n))*DD + hh*DH;
  *(float4*)(op)     = make_float4(acc2[0], acc2[1], acc2[2], acc2[3]);
  *(float4*)(op + 4) = make_float4(acc2[4], acc2[5], acc2[6], acc2[7]);
}

// ---------------------------------------------------------------------------
extern "C" void kernel_launch(void* const* d_in, const int* in_sizes, int n_in,
                              void* d_out, int out_size, void* d_ws, size_t ws_size,
                              hipStream_t stream) {
  (void)in_sizes; (void)n_in; (void)out_size; (void)ws_size;
  const float* x   = (const float*)d_in[0];
  const float* ox  = (const float*)d_in[1];
  const float* sW  = (const float*)d_in[2];
  const float* sb  = (const float*)d_in[3];
  const float* Wq  = (const float*)d_in[4];
  const float* Wk  = (const float*)d_in[5];
  const float* Wv  = (const float*)d_in[6];
  const float* Wo  = (const float*)d_in[7];
  const float* g1  = (const float*)d_in[8];
  const float* b1n = (const float*)d_in[9];
  const float* g2  = (const float*)d_in[10];
  const float* b2n = (const float*)d_in[11];
  const float* W1  = (const float*)d_in[12];
  const float* bf1 = (const float*)d_in[13];
  const float* W2  = (const float*)d_in[14];
  const float* bf2 = (const float*)d_in[15];
  float* out = (float*)d_out;
  float* ws  = (float*)d_ws;

  decomp_prep_kernel<<<272, 256, 0, stream>>>(x, ox, sb, g1, b1n, Wk, Wv, ws);
  qkv_kernel<<<BB*SS*NCH*4/256, 256, 0, stream>>>(ws, Wq, Wk, Wv, g1, b1n, sW, sb);
  attn_ffn_kernel<<<BB*NCH*2, 512, 0, stream>>>(ws, sW, sb, Wo, g2, b2n,
                                                W1, bf1, W2, bf2, out);
}

// Round 7
// 155.632 us; speedup vs baseline: 1.2943x; 1.2943x over previous
//
#include <hip/hip_runtime.h>
#include <math.h>

#define BB 16
#define SS 256
#define CC 17
#define NCH 16
#define DD 32
#define DFFN 64
#define HH 4
#define DH 8
#define EE 4

// ws layout (4-byte units):
//  [16 ..143]  K0[e][d]   [144..271] V0[e][d]
//  [512..66047]  XNS[b][s][n]
//  ints at WS_SPI: SP[b][p] (4096), OFF[b][e] (64)
//  WS_Q:   q fp32, prescaled by 1/sqrt(8)*log2(e)   [(b,p,n)][hh][8]
//  WS_KVU: k/v packed f16: [(b,n)][p][hh][k:4u v:4u]
//  WS_WT:  qkv weight image (6144 uints): WqT/WkT/WvT, rows (e*32+dd*4+hh)*16
//  WS_WL:  attn weight image (10240 uints): WoT 2048 | W1T 4096 | W2T 2 planes
#define WS_K0 16
#define WS_V0 144
#define WS_XNS 512
#define WS_SPI (WS_XNS + BB*SS*NCH)          // 66048
#define WS_Q   (WS_SPI + BB*SS + 64)         // 70208
#define WS_KVU (WS_Q + BB*SS*NCH*DD)         // 2167360
#define WS_WT  (WS_KVU + BB*SS*NCH*32)       // 4264512
#define WS_WL  (WS_WT + 6144)                // 4270656

#define PRE 0.51006977f   // (1/sqrt(8)) * log2(e)

typedef __fp16 hv2 __attribute__((ext_vector_type(2)));

__device__ __forceinline__ unsigned pkh2(float a, float b) {
  hv2 r = __builtin_amdgcn_cvt_pkrtz(a, b);
  unsigned u; __builtin_memcpy(&u, &r, 4);
  return u;
}
__device__ __forceinline__ float fd2(unsigned a, unsigned b, float c) {
  hv2 av, bv;
  __builtin_memcpy(&av, &a, 4);
  __builtin_memcpy(&bv, &b, 4);
  return __builtin_amdgcn_fdot2(av, bv, c, false);
}
__device__ __forceinline__ float h2lo(unsigned u) {
  hv2 v; __builtin_memcpy(&v, &u, 4); return (float)v[0];
}
__device__ __forceinline__ float h2hi(unsigned u) {
  hv2 v; __builtin_memcpy(&v, &u, 4); return (float)v[1];
}

// ---------------------------------------------------------------------------
// Kernel 1: decomp (blocks 0..255) + prep (256..271) + weight-image convert
// (272..287). 256 threads.
// ---------------------------------------------------------------------------
__global__ void decomp_prep_kernel(const float* __restrict__ x,
                                   const float* __restrict__ ox,
                                   const float* __restrict__ sb,
                                   const float* __restrict__ g1,
                                   const float* __restrict__ bb1,
                                   const float* __restrict__ Wq,
                                   const float* __restrict__ Wk,
                                   const float* __restrict__ Wv,
                                   const float* __restrict__ Wo,
                                   const float* __restrict__ W1,
                                   const float* __restrict__ W2,
                                   float* __restrict__ ws) {
  const int t = threadIdx.x;  // 256
  if (blockIdx.x < 256) {
    // ---------------- decomposition ----------------
    const int b = blockIdx.x / NCH;
    const int c = blockIdx.x % NCH;
    __shared__ float xs[SS];
    __shared__ float pr[256], pi[256];
    __shared__ float amp[129];
    __shared__ float2 YY[129];
    __shared__ float sth;
    xs[t] = x[(b*SS + t)*CC + c];
    __syncthreads();
    const float TH0 = 0.024543692606170259f;  // 2*pi/256
    {
      const int f = (t & 127) + 1;
      const int half = t >> 7;
      float s1, c1; sincosf(TH0*(float)f, &s1, &c1);
      const int ph0 = (f * half * 128) & 255;
      float cr, si; sincosf(TH0*(float)ph0, &si, &cr);
      float xr = 0.f, xi = 0.f;
      for (int s2 = 0; s2 < 128; ++s2) {
        float xvv = xs[half*128 + s2];
        xr += xvv * cr;
        xi -= xvv * si;
        float nc = cr*c1 - si*s1;
        si = si*c1 + cr*s1;
        cr = nc;
      }
      pr[t] = xr; pi[t] = xi;
    }
    __syncthreads();
    if (t < 128) {
      float xr = pr[t] + pr[t+128];
      float xi = pi[t] + pi[t+128];
      pr[t] = xr; pi[t] = xi;
      amp[t+1] = sqrtf(xr*xr + xi*xi);
    }
    __syncthreads();
    if (t < 64) {
      float a0 = amp[t+1], a1 = amp[t+65];
      int i0 = t+1, i1 = t+65;
      float th = -1e30f;
      for (int r = 0; r < 4; ++r) {
        float mv = (a0 > a1) ? a0 : a1;
        int   mi = (a0 > a1) ? i0 : i1;
        for (int off = 32; off > 0; off >>= 1) {
          float ov = __shfl_xor(mv, off);
          int   oi = __shfl_xor(mi, off);
          if (ov > mv || (ov == mv && oi < mi)) { mv = ov; mi = oi; }
        }
        th = mv;
        if (mi == i0) a0 = -1e30f;
        if (mi == i1) a1 = -1e30f;
      }
      if (t == 0) sth = th;
    }
    __syncthreads();
    if (t < 128) {
      const int f = t + 1;
      float wgt = (amp[f] >= sth) ? ((f == 128) ? 1.0f : 2.0f) * (1.0f/256.0f) : 0.0f;
      YY[f] = make_float2(wgt * pr[t], wgt * pi[t]);
    }
    __syncthreads();
    float s1, c1; sincosf(TH0*(float)t, &s1, &c1);
    float cr = c1, si = s1, acc = 0.f;
    for (int f = 1; f <= 128; ++f) {
      float2 y = YY[f];
      acc += y.x*cr - y.y*si;
      float nc = cr*c1 - si*s1;
      si = si*c1 + cr*s1;
      cr = nc;
    }
    const float season = acc;
    float s4 = 0.f, s8 = 0.f, s12 = 0.f;
    #pragma unroll
    for (int j = 0; j < 4; ++j)  { int p = t + j - 1; p = p < 0 ? 0 : (p > SS-1 ? SS-1 : p); s4  += xs[p]; }
    #pragma unroll
    for (int j = 0; j < 8; ++j)  { int p = t + j - 3; p = p < 0 ? 0 : (p > SS-1 ? SS-1 : p); s8  += xs[p]; }
    #pragma unroll
    for (int j = 0; j < 12; ++j) { int p = t + j - 5; p = p < 0 ? 0 : (p > SS-1 ? SS-1 : p); s12 += xs[p]; }
    float trend = (s4 * 0.25f + s8 * 0.125f + s12 * (1.0f/12.0f)) * (1.0f/3.0f);
    ws[WS_XNS + (b*SS + t)*NCH + c] = xs[t] + season + trend;
  } else if (blockIdx.x < 272) {
    // ---------------- prep ----------------
    const int b = blockIdx.x - 256;
    __shared__ float red[8];
    __shared__ int asg[SS];
    __shared__ int cnt[EE];
    __shared__ float z0[EE*DD];
    float mn = 3e38f, mx = -3e38f;
    for (int i = t; i < BB*SS; i += 256) {
      float v = ox[2*i + 1];
      mn = fminf(mn, v); mx = fmaxf(mx, v);
    }
    for (int off = 32; off > 0; off >>= 1) {
      mn = fminf(mn, __shfl_xor(mn, off));
      mx = fmaxf(mx, __shfl_xor(mx, off));
    }
    if ((t & 63) == 0) { red[(t>>6)*2] = mn; red[(t>>6)*2+1] = mx; }
    __syncthreads();
    mn = fminf(fminf(red[0], red[2]), fminf(red[4], red[6]));
    mx = fmaxf(fmaxf(red[1], red[3]), fmaxf(red[5], red[7]));
    const float step = (mx - mn) * 0.25f;
    const float e1 = mn + step, e2 = mn + 2.f*step, e3 = mn + 3.f*step;
    float sc = ox[(b*SS + t)*2 + 1];
    asg[t] = (sc >= e1) + (sc >= e2) + (sc >= e3);
    __syncthreads();
    if (t < EE) {
      int c = 0;
      for (int s2 = 0; s2 < SS; ++s2) c += (asg[s2] == t);
      cnt[t] = c;
    }
    __syncthreads();
    int* SPw  = (int*)ws + WS_SPI;
    int* OFFw = SPw + BB*SS;
    if (t < EE) {
      int off = 0;
      for (int i = 0; i < t; ++i) off += cnt[i];
      OFFw[b*EE + t] = off;
      int kp = off;
      for (int s2 = 0; s2 < SS; ++s2) if (asg[s2] == t) SPw[b*SS + (kp++)] = s2;
    }
    if (t < 128) {
      int ee = t >> 5, d = t & 31;
      float m = 0.f;
      for (int i = 0; i < DD; ++i) m += sb[i];
      m *= (1.0f/DD);
      float var = 0.f;
      for (int i = 0; i < DD; ++i) { float df = sb[i]-m; var += df*df; }
      var *= (1.0f/DD);
      float rs = rsqrtf(var + 1e-5f);
      z0[ee*DD + d] = (sb[d]-m)*rs*g1[ee*DD+d] + bb1[ee*DD+d];
    }
    __syncthreads();
    if (b == 0 && t < 128) {
      int ee = t >> 5, d = t & 31;
      float k0 = 0.f, v0 = 0.f;
      for (int i = 0; i < DD; ++i) {
        float zz = z0[ee*DD + i];
        k0 += zz * Wk[ee*DD*DD + i*DD + d];
        v0 += zz * Wv[ee*DD*DD + i*DD + d];
      }
      ws[WS_K0 + ee*DD + d] = k0;
      ws[WS_V0 + ee*DD + d] = v0;
    }
  } else {
    // ---------------- weight-image conversion (one-shot transpose) --------
    unsigned* img = (unsigned*)ws + WS_WT;
    const int base_u = (blockIdx.x - 272)*1024;
    #pragma unroll
    for (int i = 0; i < 4; ++i) {
      int u = base_u + i*256 + t;
      unsigned val;
      if (u < 6144) {                    // Wq/Wk/Wv T
        int mat = u >> 11, r = u & 2047;
        int row = r >> 4, ip = r & 15;
        int e = row >> 5, q = row & 31;
        int d = (q & 3)*8 + (q >> 2);
        const float* Wm = (mat == 0) ? Wq : (mat == 1) ? Wk : Wv;
        const float* src = Wm + e*1024 + d;
        val = pkh2(src[ip*64], src[ip*64 + 32]);
      } else {
        int v = u - 6144;
        if (v < 2048) {                  // WoT
          int row = v >> 4, ip = v & 15;
          int e = row >> 5, q = row & 31;
          int d = (q & 3)*8 + (q >> 2);
          const float* src = Wo + e*1024 + d;
          val = pkh2(src[ip*64], src[ip*64 + 32]);
        } else if (v < 6144) {           // W1T
          int r = v - 2048;
          int row = r >> 4, ip = r & 15;
          int e = row >> 6, q = row & 63;
          int j = (q & 3)*16 + (q >> 2);
          const float* src = W1 + e*2048 + j;
          val = pkh2(src[ip*128], src[ip*128 + 64]);
        } else {                         // W2T (two planes)
          int r = v - 6144;
          int a = r >> 11, rr = r & 2047;
          int row = rr >> 4, ip = rr & 15;
          int e = row >> 5, q = row & 31;
          int d = (q & 3)*8 + (q >> 2);
          int jp = a*16 + ip;
          const float* src = W2 + e*2048 + d;
          val = pkh2(src[2*jp*32], src[(2*jp+1)*32]);
        }
      }
      img[u] = val;
    }
  }
}

// ---------------------------------------------------------------------------
// Kernel 2: qkv via fdot2; weights staged by coalesced copy of WS_WT image.
// ---------------------------------------------------------------------------
__launch_bounds__(256, 4)
__global__ void qkv_kernel(float* __restrict__ ws,
    const float* __restrict__ g1, const float* __restrict__ bb1,
    const float* __restrict__ sW, const float* __restrict__ sb) {
  __shared__ unsigned wT[6144];  // WqT [0,2048) WkT [2048,4096) WvT [4096,6144)
  const int t = threadIdx.x;
  {
    const uint4* simg = (const uint4*)((const unsigned*)ws + WS_WT);
    uint4* dst = (uint4*)wT;
    #pragma unroll
    for (int i = 0; i < 6; ++i) dst[i*256 + t] = simg[i*256 + t];
  }
  const int gI = blockIdx.x*256 + t;
  const int hh = gI & 3;
  const int pos = gI >> 2;               // (b,p,n)
  const int n = pos & 15;
  const int p = (pos >> 4) & 255;
  const int b = pos >> 12;
  const int* SP  = (const int*)ws + WS_SPI;
  const int* OFF = SP + BB*SS;
  const int o1 = OFF[b*4+1], o2 = OFF[b*4+2], o3 = OFF[b*4+3];
  const int e = (p >= o1) + (p >= o2) + (p >= o3);
  const int s = SP[b*SS + p];
  const float xv = ws[WS_XNS + (b*SS + s)*NCH + n];

  float h[DD];
  #pragma unroll
  for (int d = 0; d < DD; ++d) h[d] = xv * sW[d] + sb[d];
  float m = 0.f;
  #pragma unroll
  for (int d = 0; d < DD; ++d) m += h[d];
  m *= (1.0f/DD);
  float var = 0.f;
  #pragma unroll
  for (int d = 0; d < DD; ++d) { float df = h[d]-m; var += df*df; }
  var *= (1.0f/DD);
  float rs = rsqrtf(var + 1e-5f);
  unsigned zp[16];
  #pragma unroll
  for (int ip = 0; ip < 16; ++ip) {
    float za = (h[2*ip]  -m)*rs*g1[e*DD+2*ip]   + bb1[e*DD+2*ip];
    float zb = (h[2*ip+1]-m)*rs*g1[e*DD+2*ip+1] + bb1[e*DD+2*ip+1];
    zp[ip] = pkh2(za, zb);
  }
  __syncthreads();

  float q[DH], kk[DH], vv[DH];
  #pragma unroll
  for (int dd = 0; dd < DH; ++dd) {
    const int row16 = (e*32 + dd*4 + hh)*16;    // permuted: hh in low bits
    const uint4* rq = (const uint4*)&wT[row16];
    const uint4* rk = (const uint4*)&wT[2048 + row16];
    const uint4* rv = (const uint4*)&wT[4096 + row16];
    float aq = 0.f, ak = 0.f, av = 0.f;
    #pragma unroll
    for (int g4 = 0; g4 < 4; ++g4) {
      uint4 wq4 = rq[g4], wk4 = rk[g4], wv4 = rv[g4];
      aq = fd2(zp[4*g4+0], wq4.x, aq); aq = fd2(zp[4*g4+1], wq4.y, aq);
      aq = fd2(zp[4*g4+2], wq4.z, aq); aq = fd2(zp[4*g4+3], wq4.w, aq);
      ak = fd2(zp[4*g4+0], wk4.x, ak); ak = fd2(zp[4*g4+1], wk4.y, ak);
      ak = fd2(zp[4*g4+2], wk4.z, ak); ak = fd2(zp[4*g4+3], wk4.w, ak);
      av = fd2(zp[4*g4+0], wv4.x, av); av = fd2(zp[4*g4+1], wv4.y, av);
      av = fd2(zp[4*g4+2], wv4.z, av); av = fd2(zp[4*g4+3], wv4.w, av);
    }
    q[dd] = aq; kk[dd] = ak; vv[dd] = av;
  }
  float* qp = ws + WS_Q + pos*32 + hh*DH;
  ((float4*)qp)[0] = make_float4(q[0]*PRE, q[1]*PRE, q[2]*PRE, q[3]*PRE);
  ((float4*)qp)[1] = make_float4(q[4]*PRE, q[5]*PRE, q[6]*PRE, q[7]*PRE);
  unsigned* kvg = (unsigned*)ws + WS_KVU + ((b*NCH + n)*SS + p)*32 + hh*8;
  ((uint4*)kvg)[0] = make_uint4(pkh2(kk[0],kk[1]), pkh2(kk[2],kk[3]), pkh2(kk[4],kk[5]), pkh2(kk[6],kk[7]));
  ((uint4*)kvg)[1] = make_uint4(pkh2(vv[0],vv[1]), pkh2(vv[2],vv[3]), pkh2(vv[4],vv[5]), pkh2(vv[6],vv[7]));
}

// ---------------------------------------------------------------------------
// Kernel 3: attn + Wo + FFN via fdot2. Grid (b,n,half)=512 x 512 thr.
// kv 32 KB + weight image 40 KB = 72 KB -> 2 blocks/CU. Conflict-free rows.
// ---------------------------------------------------------------------------
__launch_bounds__(512, 4)
__global__ void attn_ffn_kernel(const float* __restrict__ ws,
    const float* __restrict__ sW, const float* __restrict__ sb,
    const float* __restrict__ g2, const float* __restrict__ bb2,
    const float* __restrict__ b1, const float* __restrict__ b2,
    float* __restrict__ out) {
  const int blk = blockIdx.x;
  const int hq = blk & 1;
  const int n = (blk >> 1) & 15;
  const int b = blk >> 5;
  const int t = threadIdx.x;
  const int wj = t >> 6;        // wave 0..7
  const int lane = t & 63;
  const int pg = lane >> 2;     // 0..15
  const int hh = lane & 3;
  const int g = hq + 2*wj;      // sorted group, strided for balance
  const int p = g*16 + pg;
  const int pb = wj*16 + pg;    // 0..127 local scratch index
  __shared__ unsigned lds[8192];     // kv; scratch aliases after attention
  __shared__ unsigned wl[10240];     // WoT 2048 | W1T 4096 | W2T 2x2048
  float* fl = (float*)lds;

  // stage kv (coalesced)
  {
    const uint4* src = (const uint4*)((const unsigned*)ws + WS_KVU + (b*NCH + n)*8192);
    uint4* dst = (uint4*)lds;
    #pragma unroll
    for (int i = 0; i < 4; ++i) dst[i*512 + t] = src[i*512 + t];
  }
  // stage weight image (coalesced)
  {
    const uint4* src = (const uint4*)((const unsigned*)ws + WS_WL);
    uint4* dst = (uint4*)wl;
    #pragma unroll
    for (int i = 0; i < 5; ++i) dst[i*512 + t] = src[i*512 + t];
  }

  const int* SP  = (const int*)ws + WS_SPI;
  const int* OFF = SP + BB*SS;
  const int o1 = OFF[b*4+1], o2 = OFF[b*4+2], o3 = OFF[b*4+3];
  const int e = (p >= o1) + (p >= o2) + (p >= o3);
  const int beg = (e==0) ? 0  : ((e==1) ? o1 : ((e==2) ? o2 : o3));
  const int end = (e==0) ? o1 : ((e==1) ? o2 : ((e==2) ? o3 : SS));
  const int s = SP[b*SS + p];

  float qf[DH];
  {
    const float* qp = ws + WS_Q + ((b*SS + p)*NCH + n)*32 + hh*DH;
    float4 qa = ((const float4*)qp)[0];
    float4 qb = ((const float4*)qp)[1];
    qf[0]=qa.x; qf[1]=qa.y; qf[2]=qa.z; qf[3]=qa.w;
    qf[4]=qb.x; qf[5]=qb.y; qf[6]=qb.z; qf[7]=qb.w;
  }
  unsigned qp2[4];
  #pragma unroll
  for (int i = 0; i < 4; ++i) qp2[i] = pkh2(qf[2*i], qf[2*i+1]);
  float s0 = 0.f;
  #pragma unroll
  for (int d = 0; d < DH; ++d) s0 += qf[d] * ws[WS_K0 + e*DD + hh*DH + d];
  float v0s[DH];
  #pragma unroll
  for (int d = 0; d < DH; ++d) v0s[d] = ws[WS_V0 + e*DD + hh*DH + d];
  __syncthreads();   // kv + weights staged

  float wsum = 0.f;
  float o[DH] = {0,0,0,0,0,0,0,0};
  for (int jk = beg; jk < end; ++jk) {
    uint4 ku = *(const uint4*)&lds[jk*32 + hh*8];
    uint4 vu = *(const uint4*)&lds[jk*32 + hh*8 + 4];
    float a = 0.f;
    a = fd2(qp2[0], ku.x, a); a = fd2(qp2[1], ku.y, a);
    a = fd2(qp2[2], ku.z, a); a = fd2(qp2[3], ku.w, a);
    float w = __builtin_amdgcn_exp2f(a);
    wsum += w;
    o[0] += w*h2lo(vu.x); o[1] += w*h2hi(vu.x);
    o[2] += w*h2lo(vu.y); o[3] += w*h2hi(vu.y);
    o[4] += w*h2lo(vu.z); o[5] += w*h2hi(vu.z);
    o[6] += w*h2lo(vu.w); o[7] += w*h2hi(vu.w);
  }
  const int nmis = SS - (end - beg);
  float w0 = (float)nmis * __builtin_amdgcn_exp2f(s0);
  wsum += w0;
  #pragma unroll
  for (int d = 0; d < DH; ++d) o[d] += w0 * v0s[d];
  float inv = 1.0f / wsum;
  #pragma unroll
  for (int d = 0; d < DH; ++d) o[d] *= inv;
  __syncthreads();   // all kv reads done; scratch may overwrite

  // o exchange (fp32, stride 33)
  #pragma unroll
  for (int d = 0; d < DH; ++d) fl[pb*33 + hh*DH + d] = o[d];
  __syncthreads();
  unsigned ovp[16];
  #pragma unroll
  for (int ip = 0; ip < 16; ++ip) ovp[ip] = pkh2(fl[pb*33 + 2*ip], fl[pb*33 + 2*ip+1]);

  // Wo + residual
  const float xv = ws[WS_XNS + (b*SS + s)*NCH + n];
  float acc[DH];
  #pragma unroll
  for (int dd = 0; dd < DH; ++dd) {
    int d = hh*DH + dd;
    const uint4* row = (const uint4*)&wl[(e*32 + dd*4 + hh)*16];
    float a = xv * sW[d] + sb[d];
    #pragma unroll
    for (int g4 = 0; g4 < 4; ++g4) {
      uint4 w4 = row[g4];
      a = fd2(ovp[4*g4+0], w4.x, a); a = fd2(ovp[4*g4+1], w4.y, a);
      a = fd2(ovp[4*g4+2], w4.z, a); a = fd2(ovp[4*g4+3], w4.w, a);
    }
    acc[dd] = a;
  }
  __syncthreads();   // o reads done; reuse region for h2
  #pragma unroll
  for (int dd = 0; dd < DH; ++dd) fl[pb*33 + hh*DH + dd] = acc[dd];
  __syncthreads();

  float h2r[DD];
  #pragma unroll
  for (int i = 0; i < DD; ++i) h2r[i] = fl[pb*33 + i];
  float m = 0.f;
  #pragma unroll
  for (int d = 0; d < DD; ++d) m += h2r[d];
  m *= (1.0f/DD);
  float var = 0.f;
  #pragma unroll
  for (int d = 0; d < DD; ++d) { float df = h2r[d]-m; var += df*df; }
  var *= (1.0f/DD);
  float rs = rsqrtf(var + 1e-5f);
  unsigned zp2[16];
  #pragma unroll
  for (int ip = 0; ip < 16; ++ip) {
    float za = (h2r[2*ip]  -m)*rs*g2[e*DD+2*ip]   + bb2[e*DD+2*ip];
    float zb = (h2r[2*ip+1]-m)*rs*g2[e*DD+2*ip+1] + bb2[e*DD+2*ip+1];
    zp2[ip] = pkh2(za, zb);
  }
  float hres[DH];
  #pragma unroll
  for (int dd = 0; dd < DH; ++dd) hres[dd] = h2r[hh*DH + dd];
  __syncthreads();   // h2 reads done; reuse region for f

  // FFN1: f[hh*16 .. +16)
  float f[16];
  #pragma unroll
  for (int jj = 0; jj < 16; ++jj) {
    const uint4* row = (const uint4*)&wl[2048 + (e*64 + jj*4 + hh)*16];
    float a = b1[e*DFFN + hh*16 + jj];
    #pragma unroll
    for (int g4 = 0; g4 < 4; ++g4) {
      uint4 w4 = row[g4];
      a = fd2(zp2[4*g4+0], w4.x, a); a = fd2(zp2[4*g4+1], w4.y, a);
      a = fd2(zp2[4*g4+2], w4.z, a); a = fd2(zp2[4*g4+3], w4.w, a);
    }
    f[jj] = fmaxf(a, 0.0f);
  }
  // f exchange as f16 pairs, row stride 36 uints, uint4 stores
  {
    uint4 fa = make_uint4(pkh2(f[0],f[1]), pkh2(f[2],f[3]), pkh2(f[4],f[5]), pkh2(f[6],f[7]));
    uint4 fb = make_uint4(pkh2(f[8],f[9]), pkh2(f[10],f[11]), pkh2(f[12],f[13]), pkh2(f[14],f[15]));
    *(uint4*)&lds[pb*36 + hh*8]     = fa;
    *(uint4*)&lds[pb*36 + hh*8 + 4] = fb;
  }
  __syncthreads();

  // FFN2 + residual + b2 (W2T in two planes for conflict-free rows)
  uint4 fpr[8];
  #pragma unroll
  for (int g4 = 0; g4 < 8; ++g4) fpr[g4] = *(const uint4*)&lds[pb*36 + 4*g4];
  float acc2[DH];
  #pragma unroll
  for (int dd = 0; dd < DH; ++dd) {
    int d = hh*DH + dd;
    const int row16 = (e*32 + dd*4 + hh)*16;
    float a = hres[dd] + b2[e*DD + d];
    #pragma unroll
    for (int g4 = 0; g4 < 8; ++g4) {
      const int plane = (g4 >> 2);
      uint4 w4 = *(const uint4*)&wl[6144 + plane*2048 + row16 + 4*(g4 & 3)];
      uint4 fq = fpr[g4];
      a = fd2(fq.x, w4.x, a); a = fd2(fq.y, w4.y, a);
      a = fd2(fq.z, w4.z, a); a = fd2(fq.w, w4.w, a);
    }
    acc2[dd] = a;
  }
  float* op = out + ((size_t)((b*SS + s)*NCH + n))*DD + hh*DH;
  *(float4*)(op)     = make_float4(acc2[0], acc2[1], acc2[2], acc2[3]);
  *(float4*)(op + 4) = make_float4(acc2[4], acc2[5], acc2[6], acc2[7]);
}

// ---------------------------------------------------------------------------
extern "C" void kernel_launch(void* const* d_in, const int* in_sizes, int n_in,
                              void* d_out, int out_size, void* d_ws, size_t ws_size,
                              hipStream_t stream) {
  (void)in_sizes; (void)n_in; (void)out_size; (void)ws_size;
  const float* x   = (const float*)d_in[0];
  const float* ox  = (const float*)d_in[1];
  const float* sW  = (const float*)d_in[2];
  const float* sb  = (const float*)d_in[3];
  const float* Wq  = (const float*)d_in[4];
  const float* Wk  = (const float*)d_in[5];
  const float* Wv  = (const float*)d_in[6];
  const float* Wo  = (const float*)d_in[7];
  const float* g1  = (const float*)d_in[8];
  const float* b1n = (const float*)d_in[9];
  const float* g2  = (const float*)d_in[10];
  const float* b2n = (const float*)d_in[11];
  const float* W1  = (const float*)d_in[12];
  const float* bf1 = (const float*)d_in[13];
  const float* W2  = (const float*)d_in[14];
  const float* bf2 = (const float*)d_in[15];
  float* out = (float*)d_out;
  float* ws  = (float*)d_ws;

  decomp_prep_kernel<<<288, 256, 0, stream>>>(x, ox, sb, g1, b1n,
                                              Wq, Wk, Wv, Wo, W1, W2, ws);
  qkv_kernel<<<BB*SS*NCH*4/256, 256, 0, stream>>>(ws, g1, b1n, sW, sb);
  attn_ffn_kernel<<<BB*NCH*2, 512, 0, stream>>>(ws, sW, sb, g2, b2n,
                                                bf1, bf2, out);
}

// Round 8
// 145.564 us; speedup vs baseline: 1.3838x; 1.0692x over previous
//
#include <hip/hip_runtime.h>
#include <math.h>

#define BB 16
#define SS 256
#define CC 17
#define NCH 16
#define DD 32
#define DFFN 64
#define HH 4
#define DH 8
#define EE 4

// ws layout (4-byte units):
//  [16 ..143]  K0[e][d]   [144..271] V0[e][d]
//  [512..66047]  XNS[b][s][n]
//  ints at WS_SPI: SP[b][p] (4096), OFF[b][e] (64)
//  WS_WT: weight images (16384 uints, contiguous):
//         WqT/WkT/WvT 6144 | WoT 2048 | W1T 4096 | W2T 2x2048
#define WS_K0 16
#define WS_V0 144
#define WS_XNS 512
#define WS_SPI (WS_XNS + BB*SS*NCH)          // 66048
#define WS_WT  (WS_SPI + BB*SS + 64)         // 70208
#define WS_WL  (WS_WT + 6144)

#define PRE 0.51006977f   // (1/sqrt(8)) * log2(e)

typedef __fp16 hv2 __attribute__((ext_vector_type(2)));

__device__ __forceinline__ unsigned pkh2(float a, float b) {
  hv2 r = __builtin_amdgcn_cvt_pkrtz(a, b);
  unsigned u; __builtin_memcpy(&u, &r, 4);
  return u;
}
__device__ __forceinline__ float fd2(unsigned a, unsigned b, float c) {
  hv2 av, bv;
  __builtin_memcpy(&av, &a, 4);
  __builtin_memcpy(&bv, &b, 4);
  return __builtin_amdgcn_fdot2(av, bv, c, false);
}
__device__ __forceinline__ float h2lo(unsigned u) {
  hv2 v; __builtin_memcpy(&v, &u, 4); return (float)v[0];
}
__device__ __forceinline__ float h2hi(unsigned u) {
  hv2 v; __builtin_memcpy(&v, &u, 4); return (float)v[1];
}

// ---------------------------------------------------------------------------
// Kernel 1 (1024 thr): decomp (blocks 0..255, 32-iter rotator chains),
// prep (256..271), weight-image convert (272..275).
// ---------------------------------------------------------------------------
__launch_bounds__(1024)
__global__ void decomp_prep_kernel(const float* __restrict__ x,
                                   const float* __restrict__ ox,
                                   const float* __restrict__ sb,
                                   const float* __restrict__ g1,
                                   const float* __restrict__ bb1,
                                   const float* __restrict__ Wq,
                                   const float* __restrict__ Wk,
                                   const float* __restrict__ Wv,
                                   const float* __restrict__ Wo,
                                   const float* __restrict__ W1,
                                   const float* __restrict__ W2,
                                   float* __restrict__ ws) {
  const int t = threadIdx.x;  // 1024
  if (blockIdx.x < 256) {
    // ---------------- decomposition ----------------
    const int b = blockIdx.x / NCH;
    const int c = blockIdx.x % NCH;
    __shared__ float xs[SS];
    __shared__ float prr[1024], pii[1024];
    __shared__ float amp[129];
    __shared__ float2 YY[129];
    __shared__ float sth;
    if (t < SS) xs[t] = x[(b*SS + t)*CC + c];
    __syncthreads();
    const float TH0 = 0.024543692606170259f;  // 2*pi/256
    {
      const int f = (t & 127) + 1;
      const int chunk = t >> 7;          // 0..7
      const int s0 = chunk * 32;
      const int ph0 = (f * s0) & 255;
      float si, cr; sincosf(TH0*(float)ph0, &si, &cr);
      float s1, c1; sincosf(TH0*(float)f, &s1, &c1);
      float xr = 0.f, xi = 0.f;
      #pragma unroll 4
      for (int k = 0; k < 32; ++k) {
        float xvv = xs[s0 + k];
        xr += xvv * cr;
        xi -= xvv * si;
        float nc = cr*c1 - si*s1;
        si = si*c1 + cr*s1;
        cr = nc;
      }
      prr[t] = xr; pii[t] = xi;
    }
    __syncthreads();
    if (t < 128) {
      float xr = 0.f, xi = 0.f;
      #pragma unroll
      for (int k2 = 0; k2 < 8; ++k2) { xr += prr[t + 128*k2]; xi += pii[t + 128*k2]; }
      prr[t] = xr; pii[t] = xi;
      amp[t+1] = sqrtf(xr*xr + xi*xi);
    }
    __syncthreads();
    if (t < 64) {   // wave 0: top-4 knockout
      float a0 = amp[t+1], a1 = amp[t+65];
      int i0 = t+1, i1 = t+65;
      float th = -1e30f;
      for (int r = 0; r < 4; ++r) {
        float mv = (a0 > a1) ? a0 : a1;
        int   mi = (a0 > a1) ? i0 : i1;
        for (int off = 32; off > 0; off >>= 1) {
          float ov = __shfl_xor(mv, off);
          int   oi = __shfl_xor(mi, off);
          if (ov > mv || (ov == mv && oi < mi)) { mv = ov; mi = oi; }
        }
        th = mv;
        if (mi == i0) a0 = -1e30f;
        if (mi == i1) a1 = -1e30f;
      }
      if (t == 0) sth = th;
    }
    __syncthreads();
    if (t < 128) {
      const int f = t + 1;
      float wgt = (amp[f] >= sth) ? ((f == 128) ? 1.0f : 2.0f) * (1.0f/256.0f) : 0.0f;
      YY[f] = make_float2(wgt * prr[t], wgt * pii[t]);
    }
    __syncthreads();
    {
      const int s = t & 255;
      const int fc = t >> 8;             // 0..3
      const int f0 = 1 + fc*32;
      const int ph0 = (s * f0) & 255;
      float si, cr; sincosf(TH0*(float)ph0, &si, &cr);
      float s1, c1; sincosf(TH0*(float)s, &s1, &c1);
      float acc = 0.f;
      #pragma unroll 4
      for (int k = 0; k < 32; ++k) {
        float2 y = YY[f0 + k];
        acc += y.x*cr - y.y*si;
        float nc = cr*c1 - si*s1;
        si = si*c1 + cr*s1;
        cr = nc;
      }
      prr[t] = acc;
    }
    __syncthreads();
    if (t < 256) {
      float season = prr[t] + prr[t+256] + prr[t+512] + prr[t+768];
      float s4 = 0.f, s8 = 0.f, s12 = 0.f;
      #pragma unroll
      for (int j = 0; j < 4; ++j)  { int p = t + j - 1; p = p < 0 ? 0 : (p > SS-1 ? SS-1 : p); s4  += xs[p]; }
      #pragma unroll
      for (int j = 0; j < 8; ++j)  { int p = t + j - 3; p = p < 0 ? 0 : (p > SS-1 ? SS-1 : p); s8  += xs[p]; }
      #pragma unroll
      for (int j = 0; j < 12; ++j) { int p = t + j - 5; p = p < 0 ? 0 : (p > SS-1 ? SS-1 : p); s12 += xs[p]; }
      float trend = (s4 * 0.25f + s8 * 0.125f + s12 * (1.0f/12.0f)) * (1.0f/3.0f);
      ws[WS_XNS + (b*SS + t)*NCH + c] = xs[t] + season + trend;
    }
  } else if (blockIdx.x < 272) {
    // ---------------- prep ----------------
    const int b = blockIdx.x - 256;
    __shared__ float red[32];
    __shared__ int asg[SS];
    __shared__ int cnt[EE];
    __shared__ float z0[EE*DD];
    float mn = 3e38f, mx = -3e38f;
    #pragma unroll
    for (int k = 0; k < 4; ++k) {
      float v = ox[(t + k*1024)*2 + 1];
      mn = fminf(mn, v); mx = fmaxf(mx, v);
    }
    for (int off = 32; off > 0; off >>= 1) {
      mn = fminf(mn, __shfl_xor(mn, off));
      mx = fmaxf(mx, __shfl_xor(mx, off));
    }
    if ((t & 63) == 0) { red[(t>>6)*2] = mn; red[(t>>6)*2+1] = mx; }
    __syncthreads();
    mn = red[0]; mx = red[1];
    #pragma unroll
    for (int w = 1; w < 16; ++w) { mn = fminf(mn, red[w*2]); mx = fmaxf(mx, red[w*2+1]); }
    const float step = (mx - mn) * 0.25f;
    const float e1 = mn + step, e2 = mn + 2.f*step, e3 = mn + 3.f*step;
    if (t < 256) {
      float sc = ox[(b*SS + t)*2 + 1];
      asg[t] = (sc >= e1) + (sc >= e2) + (sc >= e3);
    }
    __syncthreads();
    if (t < EE) {
      int c = 0;
      for (int s2 = 0; s2 < SS; ++s2) c += (asg[s2] == t);
      cnt[t] = c;
    }
    __syncthreads();
    int* SPw  = (int*)ws + WS_SPI;
    int* OFFw = SPw + BB*SS;
    if (t < EE) {
      int off = 0;
      for (int i = 0; i < t; ++i) off += cnt[i];
      OFFw[b*EE + t] = off;
      int kp = off;
      for (int s2 = 0; s2 < SS; ++s2) if (asg[s2] == t) SPw[b*SS + (kp++)] = s2;
    }
    if (t < 128) {
      int ee = t >> 5, d = t & 31;
      float m = 0.f;
      for (int i = 0; i < DD; ++i) m += sb[i];
      m *= (1.0f/DD);
      float var = 0.f;
      for (int i = 0; i < DD; ++i) { float df = sb[i]-m; var += df*df; }
      var *= (1.0f/DD);
      float rs = rsqrtf(var + 1e-5f);
      z0[ee*DD + d] = (sb[d]-m)*rs*g1[ee*DD+d] + bb1[ee*DD+d];
    }
    __syncthreads();
    if (b == 0 && t < 128) {
      int ee = t >> 5, d = t & 31;
      float k0 = 0.f, v0 = 0.f;
      for (int i = 0; i < DD; ++i) {
        float zz = z0[ee*DD + i];
        k0 += zz * Wk[ee*DD*DD + i*DD + d];
        v0 += zz * Wv[ee*DD*DD + i*DD + d];
      }
      ws[WS_K0 + ee*DD + d] = k0;
      ws[WS_V0 + ee*DD + d] = v0;
    }
  } else {
    // ---------------- weight-image conversion ----------------
    unsigned* img = (unsigned*)ws + WS_WT;
    const int base_u = (blockIdx.x - 272)*4096;
    #pragma unroll
    for (int i = 0; i < 4; ++i) {
      int u = base_u + i*1024 + t;
      unsigned val;
      if (u < 6144) {                    // Wq/Wk/Wv T
        int mat = u >> 11, r = u & 2047;
        int row = r >> 4, ip = r & 15;
        int e = row >> 5, q = row & 31;
        int d = (q & 3)*8 + (q >> 2);
        const float* Wm = (mat == 0) ? Wq : (mat == 1) ? Wk : Wv;
        const float* src = Wm + e*1024 + d;
        val = pkh2(src[ip*64], src[ip*64 + 32]);
      } else {
        int v = u - 6144;
        if (v < 2048) {                  // WoT
          int row = v >> 4, ip = v & 15;
          int e = row >> 5, q = row & 31;
          int d = (q & 3)*8 + (q >> 2);
          const float* src = Wo + e*1024 + d;
          val = pkh2(src[ip*64], src[ip*64 + 32]);
        } else if (v < 6144) {           // W1T
          int r = v - 2048;
          int row = r >> 4, ip = r & 15;
          int e = row >> 6, q = row & 63;
          int j = (q & 3)*16 + (q >> 2);
          const float* src = W1 + e*2048 + j;
          val = pkh2(src[ip*128], src[ip*128 + 64]);
        } else {                         // W2T (two planes)
          int r = v - 6144;
          int a = r >> 11, rr = r & 2047;
          int row = rr >> 4, ip = rr & 15;
          int e = row >> 5, q = row & 31;
          int d = (q & 3)*8 + (q >> 2);
          int jp = a*16 + ip;
          const float* src = W2 + e*2048 + d;
          val = pkh2(src[2*jp*32], src[(2*jp+1)*32]);
        }
      }
      img[u] = val;
    }
  }
}

// ---------------------------------------------------------------------------
// Kernel 2: fully fused LN1+qkv+attn+Wo+FFN. Grid (b,n)=256 x 1024 thr.
// LDS 96 KB: kv [0,8192) | wT [8192,14336) | wl [14336,24576) -> 1 block/CU,
// 16 waves. Scratch exchanges alias dead kv/wT after attention.
// ---------------------------------------------------------------------------
__launch_bounds__(1024, 4)
__global__ void fused_kernel(const float* __restrict__ ws,
    const float* __restrict__ g1, const float* __restrict__ bb1,
    const float* __restrict__ sW, const float* __restrict__ sb,
    const float* __restrict__ g2, const float* __restrict__ bb2,
    const float* __restrict__ b1, const float* __restrict__ b2,
    float* __restrict__ out) {
  const int blk = blockIdx.x;
  const int n = blk & 15;
  const int b = blk >> 4;
  const int t = threadIdx.x;
  const int p = t >> 2;         // sorted position 0..255
  const int hh = t & 3;
  __shared__ unsigned lds[24576];
  float* fl = (float*)lds;
  unsigned* wT = lds + 8192;
  unsigned* wl = lds + 14336;

  // stage weight images (coalesced, 16384 uints)
  {
    const uint4* simg = (const uint4*)((const unsigned*)ws + WS_WT);
    uint4* dst = (uint4*)wT;
    #pragma unroll
    for (int i = 0; i < 4; ++i) dst[i*1024 + t] = simg[i*1024 + t];
  }

  const int* SP  = (const int*)ws + WS_SPI;
  const int* OFF = SP + BB*SS;
  const int o1 = OFF[b*4+1], o2 = OFF[b*4+2], o3 = OFF[b*4+3];
  const int e = (p >= o1) + (p >= o2) + (p >= o3);
  const int beg = (e==0) ? 0  : ((e==1) ? o1 : ((e==2) ? o2 : o3));
  const int end = (e==0) ? o1 : ((e==1) ? o2 : ((e==2) ? o3 : SS));
  const int s = SP[b*SS + p];
  const float xv = ws[WS_XNS + (b*SS + s)*NCH + n];

  // LN1 (replicated x4 per position; cheap)
  float h[DD];
  #pragma unroll
  for (int d = 0; d < DD; ++d) h[d] = xv * sW[d] + sb[d];
  float m = 0.f;
  #pragma unroll
  for (int d = 0; d < DD; ++d) m += h[d];
  m *= (1.0f/DD);
  float var = 0.f;
  #pragma unroll
  for (int d = 0; d < DD; ++d) { float df = h[d]-m; var += df*df; }
  var *= (1.0f/DD);
  float rs = rsqrtf(var + 1e-5f);
  unsigned zp[16];
  #pragma unroll
  for (int ip = 0; ip < 16; ++ip) {
    float za = (h[2*ip]  -m)*rs*g1[e*DD+2*ip]   + bb1[e*DD+2*ip];
    float zb = (h[2*ip+1]-m)*rs*g1[e*DD+2*ip+1] + bb1[e*DD+2*ip+1];
    zp[ip] = pkh2(za, zb);
  }
  __syncthreads();   // weight images staged

  // qkv for this (p, hh) slice via fdot2
  float q[DH], kk[DH], vv[DH];
  #pragma unroll
  for (int dd = 0; dd < DH; ++dd) {
    const int row16 = (e*32 + dd*4 + hh)*16;    // permuted rows: hh low bits
    const uint4* rq = (const uint4*)&wT[row16];
    const uint4* rk = (const uint4*)&wT[2048 + row16];
    const uint4* rv = (const uint4*)&wT[4096 + row16];
    float aq = 0.f, ak = 0.f, av = 0.f;
    #pragma unroll
    for (int g4 = 0; g4 < 4; ++g4) {
      uint4 wq4 = rq[g4], wk4 = rk[g4], wv4 = rv[g4];
      aq = fd2(zp[4*g4+0], wq4.x, aq); aq = fd2(zp[4*g4+1], wq4.y, aq);
      aq = fd2(zp[4*g4+2], wq4.z, aq); aq = fd2(zp[4*g4+3], wq4.w, aq);
      ak = fd2(zp[4*g4+0], wk4.x, ak); ak = fd2(zp[4*g4+1], wk4.y, ak);
      ak = fd2(zp[4*g4+2], wk4.z, ak); ak = fd2(zp[4*g4+3], wk4.w, ak);
      av = fd2(zp[4*g4+0], wv4.x, av); av = fd2(zp[4*g4+1], wv4.y, av);
      av = fd2(zp[4*g4+2], wv4.z, av); av = fd2(zp[4*g4+3], wv4.w, av);
    }
    q[dd] = aq * PRE; kk[dd] = ak; vv[dd] = av;
  }
  // write k/v to LDS (f16 packed)
  *(uint4*)&lds[p*32 + hh*8]     = make_uint4(pkh2(kk[0],kk[1]), pkh2(kk[2],kk[3]),
                                              pkh2(kk[4],kk[5]), pkh2(kk[6],kk[7]));
  *(uint4*)&lds[p*32 + hh*8 + 4] = make_uint4(pkh2(vv[0],vv[1]), pkh2(vv[2],vv[3]),
                                              pkh2(vv[4],vv[5]), pkh2(vv[6],vv[7]));
  unsigned qp2[4];
  #pragma unroll
  for (int i = 0; i < 4; ++i) qp2[i] = pkh2(q[2*i], q[2*i+1]);
  float s0 = 0.f;
  #pragma unroll
  for (int d = 0; d < DH; ++d) s0 += q[d] * ws[WS_K0 + e*DD + hh*DH + d];
  float v0s[DH];
  #pragma unroll
  for (int d = 0; d < DH; ++d) v0s[d] = ws[WS_V0 + e*DD + hh*DH + d];
  __syncthreads();   // kv staged

  float wsum = 0.f;
  float o[DH] = {0,0,0,0,0,0,0,0};
  for (int jk = beg; jk < end; ++jk) {
    uint4 ku = *(const uint4*)&lds[jk*32 + hh*8];
    uint4 vu = *(const uint4*)&lds[jk*32 + hh*8 + 4];
    float a = 0.f;
    a = fd2(qp2[0], ku.x, a); a = fd2(qp2[1], ku.y, a);
    a = fd2(qp2[2], ku.z, a); a = fd2(qp2[3], ku.w, a);
    float w = __builtin_amdgcn_exp2f(a);
    wsum += w;
    o[0] += w*h2lo(vu.x); o[1] += w*h2hi(vu.x);
    o[2] += w*h2lo(vu.y); o[3] += w*h2hi(vu.y);
    o[4] += w*h2lo(vu.z); o[5] += w*h2hi(vu.z);
    o[6] += w*h2lo(vu.w); o[7] += w*h2hi(vu.w);
  }
  const int nmis = SS - (end - beg);
  float w0 = (float)nmis * __builtin_amdgcn_exp2f(s0);
  wsum += w0;
  #pragma unroll
  for (int d = 0; d < DH; ++d) o[d] += w0 * v0s[d];
  float inv = 1.0f / wsum;
  #pragma unroll
  for (int d = 0; d < DH; ++d) o[d] *= inv;
  __syncthreads();   // all kv reads done; scratch may overwrite kv region

  // o exchange (fp32, stride 33; max index 8447 < 14336 -> safe vs wl)
  #pragma unroll
  for (int d = 0; d < DH; ++d) fl[p*33 + hh*DH + d] = o[d];
  __syncthreads();
  unsigned ovp[16];
  #pragma unroll
  for (int ip = 0; ip < 16; ++ip) ovp[ip] = pkh2(fl[p*33 + 2*ip], fl[p*33 + 2*ip+1]);

  // Wo + residual
  float acc[DH];
  #pragma unroll
  for (int dd = 0; dd < DH; ++dd) {
    int d = hh*DH + dd;
    const uint4* row = (const uint4*)&wl[(e*32 + dd*4 + hh)*16];
    float a = xv * sW[d] + sb[d];
    #pragma unroll
    for (int g4 = 0; g4 < 4; ++g4) {
      uint4 w4 = row[g4];
      a = fd2(ovp[4*g4+0], w4.x, a); a = fd2(ovp[4*g4+1], w4.y, a);
      a = fd2(ovp[4*g4+2], w4.z, a); a = fd2(ovp[4*g4+3], w4.w, a);
    }
    acc[dd] = a;
  }
  __syncthreads();   // o reads done; reuse region for h2
  #pragma unroll
  for (int dd = 0; dd < DH; ++dd) fl[p*33 + hh*DH + dd] = acc[dd];
  __syncthreads();

  float h2r[DD];
  #pragma unroll
  for (int i = 0; i < DD; ++i) h2r[i] = fl[p*33 + i];
  m = 0.f;
  #pragma unroll
  for (int d = 0; d < DD; ++d) m += h2r[d];
  m *= (1.0f/DD);
  var = 0.f;
  #pragma unroll
  for (int d = 0; d < DD; ++d) { float df = h2r[d]-m; var += df*df; }
  var *= (1.0f/DD);
  rs = rsqrtf(var + 1e-5f);
  unsigned zp2[16];
  #pragma unroll
  for (int ip = 0; ip < 16; ++ip) {
    float za = (h2r[2*ip]  -m)*rs*g2[e*DD+2*ip]   + bb2[e*DD+2*ip];
    float zb = (h2r[2*ip+1]-m)*rs*g2[e*DD+2*ip+1] + bb2[e*DD+2*ip+1];
    zp2[ip] = pkh2(za, zb);
  }
  float hres[DH];
  #pragma unroll
  for (int dd = 0; dd < DH; ++dd) hres[dd] = h2r[hh*DH + dd];
  __syncthreads();   // h2 reads done; reuse region for f

  // FFN1: f[hh*16 .. +16)
  float f[16];
  #pragma unroll
  for (int jj = 0; jj < 16; ++jj) {
    const uint4* row = (const uint4*)&wl[2048 + (e*64 + jj*4 + hh)*16];
    float a = b1[e*DFFN + hh*16 + jj];
    #pragma unroll
    for (int g4 = 0; g4 < 4; ++g4) {
      uint4 w4 = row[g4];
      a = fd2(zp2[4*g4+0], w4.x, a); a = fd2(zp2[4*g4+1], w4.y, a);
      a = fd2(zp2[4*g4+2], w4.z, a); a = fd2(zp2[4*g4+3], w4.w, a);
    }
    f[jj] = fmaxf(a, 0.0f);
  }
  // f exchange (f16 pairs, stride 36 uints; max 9211 < 14336 -> safe)
  {
    uint4 fa = make_uint4(pkh2(f[0],f[1]), pkh2(f[2],f[3]), pkh2(f[4],f[5]), pkh2(f[6],f[7]));
    uint4 fb = make_uint4(pkh2(f[8],f[9]), pkh2(f[10],f[11]), pkh2(f[12],f[13]), pkh2(f[14],f[15]));
    *(uint4*)&lds[p*36 + hh*8]     = fa;
    *(uint4*)&lds[p*36 + hh*8 + 4] = fb;
  }
  __syncthreads();

  // FFN2 + residual + b2
  uint4 fpr[8];
  #pragma unroll
  for (int g4 = 0; g4 < 8; ++g4) fpr[g4] = *(const uint4*)&lds[p*36 + 4*g4];
  float acc2[DH];
  #pragma unroll
  for (int dd = 0; dd < DH; ++dd) {
    int d = hh*DH + dd;
    const int row16 = (e*32 + dd*4 + hh)*16;
    float a = hres[dd] + b2[e*DD + d];
    #pragma unroll
    for (int g4 = 0; g4 < 8; ++g4) {
      const int plane = (g4 >> 2);
      uint4 w4 = *(const uint4*)&wl[6144 + plane*2048 + row16 + 4*(g4 & 3)];
      uint4 fq = fpr[g4];
      a = fd2(fq.x, w4.x, a); a = fd2(fq.y, w4.y, a);
      a = fd2(fq.z, w4.z, a); a = fd2(fq.w, w4.w, a);
    }
    acc2[dd] = a;
  }
  float* op = out + ((size_t)((b*SS + s)*NCH + n))*DD + hh*DH;
  *(float4*)(op)     = make_float4(acc2[0], acc2[1], acc2[2], acc2[3]);
  *(float4*)(op + 4) = make_float4(acc2[4], acc2[5], acc2[6], acc2[7]);
}

// ---------------------------------------------------------------------------
extern "C" void kernel_launch(void* const* d_in, const int* in_sizes, int n_in,
                              void* d_out, int out_size, void* d_ws, size_t ws_size,
                              hipStream_t stream) {
  (void)in_sizes; (void)n_in; (void)out_size; (void)ws_size;
  const float* x   = (const float*)d_in[0];
  const float* ox  = (const float*)d_in[1];
  const float* sW  = (const float*)d_in[2];
  const float* sb  = (const float*)d_in[3];
  const float* Wq  = (const float*)d_in[4];
  const float* Wk  = (const float*)d_in[5];
  const float* Wv  = (const float*)d_in[6];
  const float* Wo  = (const float*)d_in[7];
  const float* g1  = (const float*)d_in[8];
  const float* b1n = (const float*)d_in[9];
  const float* g2  = (const float*)d_in[10];
  const float* b2n = (const float*)d_in[11];
  const float* W1  = (const float*)d_in[12];
  const float* bf1 = (const float*)d_in[13];
  const float* W2  = (const float*)d_in[14];
  const float* bf2 = (const float*)d_in[15];
  float* out = (float*)d_out;
  float* ws  = (float*)d_ws;

  decomp_prep_kernel<<<276, 1024, 0, stream>>>(x, ox, sb, g1, b1n,
                                               Wq, Wk, Wv, Wo, W1, W2, ws);
  fused_kernel<<<BB*NCH, 1024, 0, stream>>>(ws, g1, b1n, sW, sb, g2, b2n,
                                            bf1, bf2, out);
}

// Round 9
// 139.013 us; speedup vs baseline: 1.4490x; 1.0471x over previous
//
#include <hip/hip_runtime.h>
#include <hip/hip_fp16.h>
#include <math.h>

#define BB 16
#define SS 256
#define CC 17
#define NCH 16
#define DD 32
#define DFFN 64
#define HH 4
#define DH 8
#define EE 4

// ws layout (4-byte units):
//  [16 ..143]  K0[e][d]   [144..271] V0[e][d]
//  [512..66047]  XNS[b][s][n]
//  ints at WS_SPI: SP[b][p] (4096), OFF[b][e] (64)
//  WS_WT: weight images (16384 uints, contiguous):
//         WqT/WkT/WvT 6144 | WoT 2048 | W1T 4096 | W2T 2x2048
#define WS_K0 16
#define WS_V0 144
#define WS_XNS 512
#define WS_SPI (WS_XNS + BB*SS*NCH)          // 66048
#define WS_WT  (WS_SPI + BB*SS + 64)         // 70208
#define WS_WL  (WS_WT + 6144)

#define PRE 0.51006977f   // (1/sqrt(8)) * log2(e)

typedef __fp16 hv2 __attribute__((ext_vector_type(2)));

__device__ __forceinline__ unsigned pkh2(float a, float b) {
  hv2 r = __builtin_amdgcn_cvt_pkrtz(a, b);
  unsigned u; __builtin_memcpy(&u, &r, 4);
  return u;
}
__device__ __forceinline__ float fd2(unsigned a, unsigned b, float c) {
  hv2 av, bv;
  __builtin_memcpy(&av, &a, 4);
  __builtin_memcpy(&bv, &b, 4);
  return __builtin_amdgcn_fdot2(av, bv, c, false);
}
__device__ __forceinline__ __half2 u2h2(unsigned u) {
  __half2 h; __builtin_memcpy(&h, &u, 4); return h;
}

// ---------------------------------------------------------------------------
// Kernel 1 (1024 thr): decomp (blocks 0..255, 32-iter rotator chains),
// prep (256..271), weight-image convert (272..275).  [unchanged from R8]
// ---------------------------------------------------------------------------
__launch_bounds__(1024)
__global__ void decomp_prep_kernel(const float* __restrict__ x,
                                   const float* __restrict__ ox,
                                   const float* __restrict__ sb,
                                   const float* __restrict__ g1,
                                   const float* __restrict__ bb1,
                                   const float* __restrict__ Wq,
                                   const float* __restrict__ Wk,
                                   const float* __restrict__ Wv,
                                   const float* __restrict__ Wo,
                                   const float* __restrict__ W1,
                                   const float* __restrict__ W2,
                                   float* __restrict__ ws) {
  const int t = threadIdx.x;  // 1024
  if (blockIdx.x < 256) {
    const int b = blockIdx.x / NCH;
    const int c = blockIdx.x % NCH;
    __shared__ float xs[SS];
    __shared__ float prr[1024], pii[1024];
    __shared__ float amp[129];
    __shared__ float2 YY[129];
    __shared__ float sth;
    if (t < SS) xs[t] = x[(b*SS + t)*CC + c];
    __syncthreads();
    const float TH0 = 0.024543692606170259f;  // 2*pi/256
    {
      const int f = (t & 127) + 1;
      const int chunk = t >> 7;
      const int s0 = chunk * 32;
      const int ph0 = (f * s0) & 255;
      float si, cr; sincosf(TH0*(float)ph0, &si, &cr);
      float s1, c1; sincosf(TH0*(float)f, &s1, &c1);
      float xr = 0.f, xi = 0.f;
      #pragma unroll 4
      for (int k = 0; k < 32; ++k) {
        float xvv = xs[s0 + k];
        xr += xvv * cr;
        xi -= xvv * si;
        float nc = cr*c1 - si*s1;
        si = si*c1 + cr*s1;
        cr = nc;
      }
      prr[t] = xr; pii[t] = xi;
    }
    __syncthreads();
    if (t < 128) {
      float xr = 0.f, xi = 0.f;
      #pragma unroll
      for (int k2 = 0; k2 < 8; ++k2) { xr += prr[t + 128*k2]; xi += pii[t + 128*k2]; }
      prr[t] = xr; pii[t] = xi;
      amp[t+1] = sqrtf(xr*xr + xi*xi);
    }
    __syncthreads();
    if (t < 64) {
      float a0 = amp[t+1], a1 = amp[t+65];
      int i0 = t+1, i1 = t+65;
      float th = -1e30f;
      for (int r = 0; r < 4; ++r) {
        float mv = (a0 > a1) ? a0 : a1;
        int   mi = (a0 > a1) ? i0 : i1;
        for (int off = 32; off > 0; off >>= 1) {
          float ov = __shfl_xor(mv, off);
          int   oi = __shfl_xor(mi, off);
          if (ov > mv || (ov == mv && oi < mi)) { mv = ov; mi = oi; }
        }
        th = mv;
        if (mi == i0) a0 = -1e30f;
        if (mi == i1) a1 = -1e30f;
      }
      if (t == 0) sth = th;
    }
    __syncthreads();
    if (t < 128) {
      const int f = t + 1;
      float wgt = (amp[f] >= sth) ? ((f == 128) ? 1.0f : 2.0f) * (1.0f/256.0f) : 0.0f;
      YY[f] = make_float2(wgt * prr[t], wgt * pii[t]);
    }
    __syncthreads();
    {
      const int s = t & 255;
      const int fc = t >> 8;
      const int f0 = 1 + fc*32;
      const int ph0 = (s * f0) & 255;
      float si, cr; sincosf(TH0*(float)ph0, &si, &cr);
      float s1, c1; sincosf(TH0*(float)s, &s1, &c1);
      float acc = 0.f;
      #pragma unroll 4
      for (int k = 0; k < 32; ++k) {
        float2 y = YY[f0 + k];
        acc += y.x*cr - y.y*si;
        float nc = cr*c1 - si*s1;
        si = si*c1 + cr*s1;
        cr = nc;
      }
      prr[t] = acc;
    }
    __syncthreads();
    if (t < 256) {
      float season = prr[t] + prr[t+256] + prr[t+512] + prr[t+768];
      float s4 = 0.f, s8 = 0.f, s12 = 0.f;
      #pragma unroll
      for (int j = 0; j < 4; ++j)  { int p = t + j - 1; p = p < 0 ? 0 : (p > SS-1 ? SS-1 : p); s4  += xs[p]; }
      #pragma unroll
      for (int j = 0; j < 8; ++j)  { int p = t + j - 3; p = p < 0 ? 0 : (p > SS-1 ? SS-1 : p); s8  += xs[p]; }
      #pragma unroll
      for (int j = 0; j < 12; ++j) { int p = t + j - 5; p = p < 0 ? 0 : (p > SS-1 ? SS-1 : p); s12 += xs[p]; }
      float trend = (s4 * 0.25f + s8 * 0.125f + s12 * (1.0f/12.0f)) * (1.0f/3.0f);
      ws[WS_XNS + (b*SS + t)*NCH + c] = xs[t] + season + trend;
    }
  } else if (blockIdx.x < 272) {
    const int b = blockIdx.x - 256;
    __shared__ float red[32];
    __shared__ int asg[SS];
    __shared__ int cnt[EE];
    __shared__ float z0[EE*DD];
    float mn = 3e38f, mx = -3e38f;
    #pragma unroll
    for (int k = 0; k < 4; ++k) {
      float v = ox[(t + k*1024)*2 + 1];
      mn = fminf(mn, v); mx = fmaxf(mx, v);
    }
    for (int off = 32; off > 0; off >>= 1) {
      mn = fminf(mn, __shfl_xor(mn, off));
      mx = fmaxf(mx, __shfl_xor(mx, off));
    }
    if ((t & 63) == 0) { red[(t>>6)*2] = mn; red[(t>>6)*2+1] = mx; }
    __syncthreads();
    mn = red[0]; mx = red[1];
    #pragma unroll
    for (int w = 1; w < 16; ++w) { mn = fminf(mn, red[w*2]); mx = fmaxf(mx, red[w*2+1]); }
    const float step = (mx - mn) * 0.25f;
    const float e1 = mn + step, e2 = mn + 2.f*step, e3 = mn + 3.f*step;
    if (t < 256) {
      float sc = ox[(b*SS + t)*2 + 1];
      asg[t] = (sc >= e1) + (sc >= e2) + (sc >= e3);
    }
    __syncthreads();
    if (t < EE) {
      int c = 0;
      for (int s2 = 0; s2 < SS; ++s2) c += (asg[s2] == t);
      cnt[t] = c;
    }
    __syncthreads();
    int* SPw  = (int*)ws + WS_SPI;
    int* OFFw = SPw + BB*SS;
    if (t < EE) {
      int off = 0;
      for (int i = 0; i < t; ++i) off += cnt[i];
      OFFw[b*EE + t] = off;
      int kp = off;
      for (int s2 = 0; s2 < SS; ++s2) if (asg[s2] == t) SPw[b*SS + (kp++)] = s2;
    }
    if (t < 128) {
      int ee = t >> 5, d = t & 31;
      float m = 0.f;
      for (int i = 0; i < DD; ++i) m += sb[i];
      m *= (1.0f/DD);
      float var = 0.f;
      for (int i = 0; i < DD; ++i) { float df = sb[i]-m; var += df*df; }
      var *= (1.0f/DD);
      float rs = rsqrtf(var + 1e-5f);
      z0[ee*DD + d] = (sb[d]-m)*rs*g1[ee*DD+d] + bb1[ee*DD+d];
    }
    __syncthreads();
    if (b == 0 && t < 128) {
      int ee = t >> 5, d = t & 31;
      float k0 = 0.f, v0 = 0.f;
      for (int i = 0; i < DD; ++i) {
        float zz = z0[ee*DD + i];
        k0 += zz * Wk[ee*DD*DD + i*DD + d];
        v0 += zz * Wv[ee*DD*DD + i*DD + d];
      }
      ws[WS_K0 + ee*DD + d] = k0;
      ws[WS_V0 + ee*DD + d] = v0;
    }
  } else {
    unsigned* img = (unsigned*)ws + WS_WT;
    const int base_u = (blockIdx.x - 272)*4096;
    #pragma unroll
    for (int i = 0; i < 4; ++i) {
      int u = base_u + i*1024 + t;
      unsigned val;
      if (u < 6144) {                    // Wq/Wk/Wv T
        int mat = u >> 11, r = u & 2047;
        int row = r >> 4, ip = r & 15;
        int e = row >> 5, q = row & 31;
        int d = (q & 3)*8 + (q >> 2);
        const float* Wm = (mat == 0) ? Wq : (mat == 1) ? Wk : Wv;
        const float* src = Wm + e*1024 + d;
        val = pkh2(src[ip*64], src[ip*64 + 32]);
      } else {
        int v = u - 6144;
        if (v < 2048) {                  // WoT
          int row = v >> 4, ip = v & 15;
          int e = row >> 5, q = row & 31;
          int d = (q & 3)*8 + (q >> 2);
          const float* src = Wo + e*1024 + d;
          val = pkh2(src[ip*64], src[ip*64 + 32]);
        } else if (v < 6144) {           // W1T
          int r = v - 2048;
          int row = r >> 4, ip = r & 15;
          int e = row >> 6, q = row & 63;
          int j = (q & 3)*16 + (q >> 2);
          const float* src = W1 + e*2048 + j;
          val = pkh2(src[ip*128], src[ip*128 + 64]);
        } else {                         // W2T (two planes)
          int r = v - 6144;
          int a = r >> 11, rr = r & 2047;
          int row = rr >> 4, ip = rr & 15;
          int e = row >> 5, q = row & 31;
          int d = (q & 3)*8 + (q >> 2);
          int jp = a*16 + ip;
          const float* src = W2 + e*2048 + d;
          val = pkh2(src[2*jp*32], src[(2*jp+1)*32]);
        }
      }
      img[u] = val;
    }
  }
}

// ---------------------------------------------------------------------------
// Kernel 2: fully fused LN1+qkv+attn+Wo+FFN. Grid (b,n)=256 x 1024 thr.
// LDS 96 KB: kv [0,8192) | wT [8192,14336) | wl [14336,24576).
// Weight staging via async global_load_lds (width 16); o-accum in pk f16.
// ---------------------------------------------------------------------------
__launch_bounds__(1024, 4)
__global__ void fused_kernel(const float* __restrict__ ws,
    const float* __restrict__ g1, const float* __restrict__ bb1,
    const float* __restrict__ sW, const float* __restrict__ sb,
    const float* __restrict__ g2, const float* __restrict__ bb2,
    const float* __restrict__ b1, const float* __restrict__ b2,
    float* __restrict__ out) {
  const int blk = blockIdx.x;
  const int n = blk & 15;
  const int b = blk >> 4;
  const int t = threadIdx.x;
  const int p = t >> 2;         // sorted position 0..255
  const int hh = t & 3;
  __shared__ unsigned lds[24576];
  float* fl = (float*)lds;
  unsigned* wT = lds + 8192;
  unsigned* wl = lds + 14336;

  // async-stage both weight images (16384 uints = 64 x 1KB chunks, 4/wave)
  {
    const unsigned* img = (const unsigned*)ws + WS_WT;
    const int wv = t >> 6;
    const int ln = t & 63;
    #pragma unroll
    for (int i = 0; i < 4; ++i) {
      const int ch = wv*4 + i;
      __builtin_amdgcn_global_load_lds(
          (const __attribute__((address_space(1))) unsigned*)(img + ch*256 + ln*4),
          (__attribute__((address_space(3))) unsigned*)(wT + ch*256 + ln*4),
          16, 0, 0);
    }
  }

  const int* SP  = (const int*)ws + WS_SPI;
  const int* OFF = SP + BB*SS;
  const int o1 = OFF[b*4+1], o2v = OFF[b*4+2], o3 = OFF[b*4+3];
  const int e = (p >= o1) + (p >= o2v) + (p >= o3);
  const int beg = (e==0) ? 0  : ((e==1) ? o1 : ((e==2) ? o2v : o3));
  const int end = (e==0) ? o1 : ((e==1) ? o2v : ((e==2) ? o3 : SS));
  const int s = SP[b*SS + p];
  const float xv = ws[WS_XNS + (b*SS + s)*NCH + n];

  // LN1 (replicated x4 per position; cheap)
  float h[DD];
  #pragma unroll
  for (int d = 0; d < DD; ++d) h[d] = xv * sW[d] + sb[d];
  float m = 0.f;
  #pragma unroll
  for (int d = 0; d < DD; ++d) m += h[d];
  m *= (1.0f/DD);
  float var = 0.f;
  #pragma unroll
  for (int d = 0; d < DD; ++d) { float df = h[d]-m; var += df*df; }
  var *= (1.0f/DD);
  float rs = rsqrtf(var + 1e-5f);
  unsigned zp[16];
  #pragma unroll
  for (int ip = 0; ip < 16; ++ip) {
    float za = (h[2*ip]  -m)*rs*g1[e*DD+2*ip]   + bb1[e*DD+2*ip];
    float zb = (h[2*ip+1]-m)*rs*g1[e*DD+2*ip+1] + bb1[e*DD+2*ip+1];
    zp[ip] = pkh2(za, zb);
  }
  __syncthreads();   // weight images staged (vmcnt drained by barrier)

  // qkv for this (p, hh) slice via fdot2
  float q[DH], kk[DH], vv[DH];
  #pragma unroll
  for (int dd = 0; dd < DH; ++dd) {
    const int row16 = (e*32 + dd*4 + hh)*16;    // permuted rows: hh low bits
    const uint4* rq = (const uint4*)&wT[row16];
    const uint4* rk = (const uint4*)&wT[2048 + row16];
    const uint4* rv = (const uint4*)&wT[4096 + row16];
    float aq = 0.f, ak = 0.f, av = 0.f;
    #pragma unroll
    for (int g4 = 0; g4 < 4; ++g4) {
      uint4 wq4 = rq[g4], wk4 = rk[g4], wv4 = rv[g4];
      aq = fd2(zp[4*g4+0], wq4.x, aq); aq = fd2(zp[4*g4+1], wq4.y, aq);
      aq = fd2(zp[4*g4+2], wq4.z, aq); aq = fd2(zp[4*g4+3], wq4.w, aq);
      ak = fd2(zp[4*g4+0], wk4.x, ak); ak = fd2(zp[4*g4+1], wk4.y, ak);
      ak = fd2(zp[4*g4+2], wk4.z, ak); ak = fd2(zp[4*g4+3], wk4.w, ak);
      av = fd2(zp[4*g4+0], wv4.x, av); av = fd2(zp[4*g4+1], wv4.y, av);
      av = fd2(zp[4*g4+2], wv4.z, av); av = fd2(zp[4*g4+3], wv4.w, av);
    }
    q[dd] = aq * PRE; kk[dd] = ak; vv[dd] = av;
  }
  // write k/v to LDS (f16 packed)
  *(uint4*)&lds[p*32 + hh*8]     = make_uint4(pkh2(kk[0],kk[1]), pkh2(kk[2],kk[3]),
                                              pkh2(kk[4],kk[5]), pkh2(kk[6],kk[7]));
  *(uint4*)&lds[p*32 + hh*8 + 4] = make_uint4(pkh2(vv[0],vv[1]), pkh2(vv[2],vv[3]),
                                              pkh2(vv[4],vv[5]), pkh2(vv[6],vv[7]));
  unsigned qp2[4];
  #pragma unroll
  for (int i = 0; i < 4; ++i) qp2[i] = pkh2(q[2*i], q[2*i+1]);
  float s0 = 0.f;
  #pragma unroll
  for (int d = 0; d < DH; ++d) s0 += q[d] * ws[WS_K0 + e*DD + hh*DH + d];
  __syncthreads();   // kv staged

  // attention: o accumulated as packed f16 pairs (v_pk_fma_f16)
  float wsum = 0.f;
  __half2 o2[4];
  #pragma unroll
  for (int i = 0; i < 4; ++i) o2[i] = u2h2(0u);
  int jk = beg;
  for (; jk + 1 < end; jk += 2) {
    uint4 ku0 = *(const uint4*)&lds[jk*32 + hh*8];
    uint4 vu0 = *(const uint4*)&lds[jk*32 + hh*8 + 4];
    uint4 ku1 = *(const uint4*)&lds[(jk+1)*32 + hh*8];
    uint4 vu1 = *(const uint4*)&lds[(jk+1)*32 + hh*8 + 4];
    float a0 = 0.f, a1 = 0.f;
    a0 = fd2(qp2[0], ku0.x, a0); a0 = fd2(qp2[1], ku0.y, a0);
    a0 = fd2(qp2[2], ku0.z, a0); a0 = fd2(qp2[3], ku0.w, a0);
    a1 = fd2(qp2[0], ku1.x, a1); a1 = fd2(qp2[1], ku1.y, a1);
    a1 = fd2(qp2[2], ku1.z, a1); a1 = fd2(qp2[3], ku1.w, a1);
    float w0f = __builtin_amdgcn_exp2f(a0);
    float w1f = __builtin_amdgcn_exp2f(a1);
    wsum += w0f + w1f;
    __half2 w20 = u2h2(pkh2(w0f, w0f));
    __half2 w21 = u2h2(pkh2(w1f, w1f));
    o2[0] = __hfma2(w20, u2h2(vu0.x), o2[0]);
    o2[1] = __hfma2(w20, u2h2(vu0.y), o2[1]);
    o2[2] = __hfma2(w20, u2h2(vu0.z), o2[2]);
    o2[3] = __hfma2(w20, u2h2(vu0.w), o2[3]);
    o2[0] = __hfma2(w21, u2h2(vu1.x), o2[0]);
    o2[1] = __hfma2(w21, u2h2(vu1.y), o2[1]);
    o2[2] = __hfma2(w21, u2h2(vu1.z), o2[2]);
    o2[3] = __hfma2(w21, u2h2(vu1.w), o2[3]);
  }
  if (jk < end) {
    uint4 ku = *(const uint4*)&lds[jk*32 + hh*8];
    uint4 vu = *(const uint4*)&lds[jk*32 + hh*8 + 4];
    float a = 0.f;
    a = fd2(qp2[0], ku.x, a); a = fd2(qp2[1], ku.y, a);
    a = fd2(qp2[2], ku.z, a); a = fd2(qp2[3], ku.w, a);
    float wf = __builtin_amdgcn_exp2f(a);
    wsum += wf;
    __half2 w2 = u2h2(pkh2(wf, wf));
    o2[0] = __hfma2(w2, u2h2(vu.x), o2[0]);
    o2[1] = __hfma2(w2, u2h2(vu.y), o2[1]);
    o2[2] = __hfma2(w2, u2h2(vu.z), o2[2]);
    o2[3] = __hfma2(w2, u2h2(vu.w), o2[3]);
  }
  // off-expert keys: constant score s0, constant value v0
  float o[DH];
  #pragma unroll
  for (int i = 0; i < 4; ++i) {
    o[2*i]   = __low2float(o2[i]);
    o[2*i+1] = __high2float(o2[i]);
  }
  const int nmis = SS - (end - beg);
  float w0 = (float)nmis * __builtin_amdgcn_exp2f(s0);
  wsum += w0;
  #pragma unroll
  for (int d = 0; d < DH; ++d) o[d] += w0 * ws[WS_V0 + e*DD + hh*DH + d];
  float inv = 1.0f / wsum;
  #pragma unroll
  for (int d = 0; d < DH; ++d) o[d] *= inv;
  __syncthreads();   // all kv reads done; scratch may overwrite kv region

  // o exchange (fp32, stride 33)
  #pragma unroll
  for (int d = 0; d < DH; ++d) fl[p*33 + hh*DH + d] = o[d];
  __syncthreads();
  unsigned ovp[16];
  #pragma unroll
  for (int ip = 0; ip < 16; ++ip) ovp[ip] = pkh2(fl[p*33 + 2*ip], fl[p*33 + 2*ip+1]);

  // Wo + residual
  float acc[DH];
  #pragma unroll
  for (int dd = 0; dd < DH; ++dd) {
    int d = hh*DH + dd;
    const uint4* row = (const uint4*)&wl[(e*32 + dd*4 + hh)*16];
    float a = xv * sW[d] + sb[d];
    #pragma unroll
    for (int g4 = 0; g4 < 4; ++g4) {
      uint4 w4 = row[g4];
      a = fd2(ovp[4*g4+0], w4.x, a); a = fd2(ovp[4*g4+1], w4.y, a);
      a = fd2(ovp[4*g4+2], w4.z, a); a = fd2(ovp[4*g4+3], w4.w, a);
    }
    acc[dd] = a;
  }
  __syncthreads();   // o reads done; reuse region for h2
  #pragma unroll
  for (int dd = 0; dd < DH; ++dd) fl[p*33 + hh*DH + dd] = acc[dd];
  __syncthreads();

  float h2r[DD];
  #pragma unroll
  for (int i = 0; i < DD; ++i) h2r[i] = fl[p*33 + i];
  m = 0.f;
  #pragma unroll
  for (int d = 0; d < DD; ++d) m += h2r[d];
  m *= (1.0f/DD);
  var = 0.f;
  #pragma unroll
  for (int d = 0; d < DD; ++d) { float df = h2r[d]-m; var += df*df; }
  var *= (1.0f/DD);
  rs = rsqrtf(var + 1e-5f);
  unsigned zp2[16];
  #pragma unroll
  for (int ip = 0; ip < 16; ++ip) {
    float za = (h2r[2*ip]  -m)*rs*g2[e*DD+2*ip]   + bb2[e*DD+2*ip];
    float zb = (h2r[2*ip+1]-m)*rs*g2[e*DD+2*ip+1] + bb2[e*DD+2*ip+1];
    zp2[ip] = pkh2(za, zb);
  }
  float hres[DH];
  #pragma unroll
  for (int dd = 0; dd < DH; ++dd) hres[dd] = h2r[hh*DH + dd];
  __syncthreads();   // h2 reads done; reuse region for f

  // FFN1: f[hh*16 .. +16)
  float f[16];
  #pragma unroll
  for (int jj = 0; jj < 16; ++jj) {
    const uint4* row = (const uint4*)&wl[2048 + (e*64 + jj*4 + hh)*16];
    float a = b1[e*DFFN + hh*16 + jj];
    #pragma unroll
    for (int g4 = 0; g4 < 4; ++g4) {
      uint4 w4 = row[g4];
      a = fd2(zp2[4*g4+0], w4.x, a); a = fd2(zp2[4*g4+1], w4.y, a);
      a = fd2(zp2[4*g4+2], w4.z, a); a = fd2(zp2[4*g4+3], w4.w, a);
    }
    f[jj] = fmaxf(a, 0.0f);
  }
  // f exchange (f16 pairs, stride 36 uints)
  {
    uint4 fa = make_uint4(pkh2(f[0],f[1]), pkh2(f[2],f[3]), pkh2(f[4],f[5]), pkh2(f[6],f[7]));
    uint4 fb = make_uint4(pkh2(f[8],f[9]), pkh2(f[10],f[11]), pkh2(f[12],f[13]), pkh2(f[14],f[15]));
    *(uint4*)&lds[p*36 + hh*8]     = fa;
    *(uint4*)&lds[p*36 + hh*8 + 4] = fb;
  }
  __syncthreads();

  // FFN2 + residual + b2
  uint4 fpr[8];
  #pragma unroll
  for (int g4 = 0; g4 < 8; ++g4) fpr[g4] = *(const uint4*)&lds[p*36 + 4*g4];
  float acc2[DH];
  #pragma unroll
  for (int dd = 0; dd < DH; ++dd) {
    int d = hh*DH + dd;
    const int row16 = (e*32 + dd*4 + hh)*16;
    float a = hres[dd] + b2[e*DD + d];
    #pragma unroll
    for (int g4 = 0; g4 < 8; ++g4) {
      const int plane = (g4 >> 2);
      uint4 w4 = *(const uint4*)&wl[6144 + plane*2048 + row16 + 4*(g4 & 3)];
      uint4 fq = fpr[g4];
      a = fd2(fq.x, w4.x, a); a = fd2(fq.y, w4.y, a);
      a = fd2(fq.z, w4.z, a); a = fd2(fq.w, w4.w, a);
    }
    acc2[dd] = a;
  }
  float* op = out + ((size_t)((b*SS + s)*NCH + n))*DD + hh*DH;
  *(float4*)(op)     = make_float4(acc2[0], acc2[1], acc2[2], acc2[3]);
  *(float4*)(op + 4) = make_float4(acc2[4], acc2[5], acc2[6], acc2[7]);
}

// ---------------------------------------------------------------------------
extern "C" void kernel_launch(void* const* d_in, const int* in_sizes, int n_in,
                              void* d_out, int out_size, void* d_ws, size_t ws_size,
                              hipStream_t stream) {
  (void)in_sizes; (void)n_in; (void)out_size; (void)ws_size;
  const float* x   = (const float*)d_in[0];
  const float* ox  = (const float*)d_in[1];
  const float* sW  = (const float*)d_in[2];
  const float* sb  = (const float*)d_in[3];
  const float* Wq  = (const float*)d_in[4];
  const float* Wk  = (const float*)d_in[5];
  const float* Wv  = (const float*)d_in[6];
  const float* Wo  = (const float*)d_in[7];
  const float* g1  = (const float*)d_in[8];
  const float* b1n = (const float*)d_in[9];
  const float* g2  = (const float*)d_in[10];
  const float* b2n = (const float*)d_in[11];
  const float* W1  = (const float*)d_in[12];
  const float* bf1 = (const float*)d_in[13];
  const float* W2  = (const float*)d_in[14];
  const float* bf2 = (const float*)d_in[15];
  float* out = (float*)d_out;
  float* ws  = (float*)d_ws;

  decomp_prep_kernel<<<276, 1024, 0, stream>>>(x, ox, sb, g1, b1n,
                                               Wq, Wk, Wv, Wo, W1, W2, ws);
  fused_kernel<<<BB*NCH, 1024, 0, stream>>>(ws, g1, b1n, sW, sb, g2, b2n,
                                            bf1, bf2, out);
}

// Round 10
// 135.596 us; speedup vs baseline: 1.4856x; 1.0252x over previous
//
#include <hip/hip_runtime.h>
#include <hip/hip_fp16.h>
#include <math.h>

#define BB 16
#define SS 256
#define CC 17
#define NCH 16
#define DD 32
#define DFFN 64
#define HH 4
#define DH 8
#define EE 4

// ws layout (4-byte units):
//  [16 ..143]  K0[e][d]   [144..271] V0[e][d]
//  [512..66047]  XNS[b][s][n]
//  ints at WS_SPI: SP[b][p] (4096), OFF[b][e] (64)
//  WS_WT: weight images (16384 uints): WqT/WkT/WvT 6144 | WoT 2048 | W1T 4096 | W2T 2x2048
#define WS_K0 16
#define WS_V0 144
#define WS_XNS 512
#define WS_SPI (WS_XNS + BB*SS*NCH)          // 66048
#define WS_WT  (WS_SPI + BB*SS + 64)         // 70208
#define WS_WL  (WS_WT + 6144)

#define PRE 0.51006977f   // (1/sqrt(8)) * log2(e)

typedef __fp16 hv2 __attribute__((ext_vector_type(2)));

__device__ __forceinline__ unsigned pkh2(float a, float b) {
  hv2 r = __builtin_amdgcn_cvt_pkrtz(a, b);
  unsigned u; __builtin_memcpy(&u, &r, 4);
  return u;
}
__device__ __forceinline__ float fd2(unsigned a, unsigned b, float c) {
  hv2 av, bv;
  __builtin_memcpy(&av, &a, 4);
  __builtin_memcpy(&bv, &b, 4);
  return __builtin_amdgcn_fdot2(av, bv, c, false);
}
__device__ __forceinline__ __half2 u2h2(unsigned u) {
  __half2 h; __builtin_memcpy(&h, &u, 4); return h;
}
// quad_perm DPP: result[lane] = src[(lane&~3) | sel[lane&3]]
template<int PAT>
__device__ __forceinline__ unsigned qdpp(unsigned v) {
  return (unsigned)__builtin_amdgcn_mov_dpp((int)v, PAT, 0xF, 0xF, true);
}
template<int PAT>
__device__ __forceinline__ float qdppf(float v) {
  return __uint_as_float(qdpp<PAT>(__float_as_uint(v)));
}
// broadcast quad-lane q to all: 0x00, 0x55, 0xAA, 0xFF
// xor1 = 0xB1, xor2 = 0x4E

// ---------------------------------------------------------------------------
// Kernel 1 (1024 thr): decomp (blocks 0..255), prep (256..271),
// weight-image convert (272..275). [unchanged from R9]
// ---------------------------------------------------------------------------
__launch_bounds__(1024)
__global__ void decomp_prep_kernel(const float* __restrict__ x,
                                   const float* __restrict__ ox,
                                   const float* __restrict__ sb,
                                   const float* __restrict__ g1,
                                   const float* __restrict__ bb1,
                                   const float* __restrict__ Wq,
                                   const float* __restrict__ Wk,
                                   const float* __restrict__ Wv,
                                   const float* __restrict__ Wo,
                                   const float* __restrict__ W1,
                                   const float* __restrict__ W2,
                                   float* __restrict__ ws) {
  const int t = threadIdx.x;  // 1024
  if (blockIdx.x < 256) {
    const int b = blockIdx.x / NCH;
    const int c = blockIdx.x % NCH;
    __shared__ float xs[SS];
    __shared__ float prr[1024], pii[1024];
    __shared__ float amp[129];
    __shared__ float2 YY[129];
    __shared__ float sth;
    if (t < SS) xs[t] = x[(b*SS + t)*CC + c];
    __syncthreads();
    const float TH0 = 0.024543692606170259f;  // 2*pi/256
    {
      const int f = (t & 127) + 1;
      const int chunk = t >> 7;
      const int s0 = chunk * 32;
      const int ph0 = (f * s0) & 255;
      float si, cr; sincosf(TH0*(float)ph0, &si, &cr);
      float s1, c1; sincosf(TH0*(float)f, &s1, &c1);
      float xr = 0.f, xi = 0.f;
      #pragma unroll 4
      for (int k = 0; k < 32; ++k) {
        float xvv = xs[s0 + k];
        xr += xvv * cr;
        xi -= xvv * si;
        float nc = cr*c1 - si*s1;
        si = si*c1 + cr*s1;
        cr = nc;
      }
      prr[t] = xr; pii[t] = xi;
    }
    __syncthreads();
    if (t < 128) {
      float xr = 0.f, xi = 0.f;
      #pragma unroll
      for (int k2 = 0; k2 < 8; ++k2) { xr += prr[t + 128*k2]; xi += pii[t + 128*k2]; }
      prr[t] = xr; pii[t] = xi;
      amp[t+1] = sqrtf(xr*xr + xi*xi);
    }
    __syncthreads();
    if (t < 64) {
      float a0 = amp[t+1], a1 = amp[t+65];
      int i0 = t+1, i1 = t+65;
      float th = -1e30f;
      for (int r = 0; r < 4; ++r) {
        float mv = (a0 > a1) ? a0 : a1;
        int   mi = (a0 > a1) ? i0 : i1;
        for (int off = 32; off > 0; off >>= 1) {
          float ov = __shfl_xor(mv, off);
          int   oi = __shfl_xor(mi, off);
          if (ov > mv || (ov == mv && oi < mi)) { mv = ov; mi = oi; }
        }
        th = mv;
        if (mi == i0) a0 = -1e30f;
        if (mi == i1) a1 = -1e30f;
      }
      if (t == 0) sth = th;
    }
    __syncthreads();
    if (t < 128) {
      const int f = t + 1;
      float wgt = (amp[f] >= sth) ? ((f == 128) ? 1.0f : 2.0f) * (1.0f/256.0f) : 0.0f;
      YY[f] = make_float2(wgt * prr[t], wgt * pii[t]);
    }
    __syncthreads();
    {
      const int s = t & 255;
      const int fc = t >> 8;
      const int f0 = 1 + fc*32;
      const int ph0 = (s * f0) & 255;
      float si, cr; sincosf(TH0*(float)ph0, &si, &cr);
      float s1, c1; sincosf(TH0*(float)s, &s1, &c1);
      float acc = 0.f;
      #pragma unroll 4
      for (int k = 0; k < 32; ++k) {
        float2 y = YY[f0 + k];
        acc += y.x*cr - y.y*si;
        float nc = cr*c1 - si*s1;
        si = si*c1 + cr*s1;
        cr = nc;
      }
      prr[t] = acc;
    }
    __syncthreads();
    if (t < 256) {
      float season = prr[t] + prr[t+256] + prr[t+512] + prr[t+768];
      float s4 = 0.f, s8 = 0.f, s12 = 0.f;
      #pragma unroll
      for (int j = 0; j < 4; ++j)  { int p = t + j - 1; p = p < 0 ? 0 : (p > SS-1 ? SS-1 : p); s4  += xs[p]; }
      #pragma unroll
      for (int j = 0; j < 8; ++j)  { int p = t + j - 3; p = p < 0 ? 0 : (p > SS-1 ? SS-1 : p); s8  += xs[p]; }
      #pragma unroll
      for (int j = 0; j < 12; ++j) { int p = t + j - 5; p = p < 0 ? 0 : (p > SS-1 ? SS-1 : p); s12 += xs[p]; }
      float trend = (s4 * 0.25f + s8 * 0.125f + s12 * (1.0f/12.0f)) * (1.0f/3.0f);
      ws[WS_XNS + (b*SS + t)*NCH + c] = xs[t] + season + trend;
    }
  } else if (blockIdx.x < 272) {
    const int b = blockIdx.x - 256;
    __shared__ float red[32];
    __shared__ int asg[SS];
    __shared__ int cnt[EE];
    __shared__ float z0[EE*DD];
    float mn = 3e38f, mx = -3e38f;
    #pragma unroll
    for (int k = 0; k < 4; ++k) {
      float v = ox[(t + k*1024)*2 + 1];
      mn = fminf(mn, v); mx = fmaxf(mx, v);
    }
    for (int off = 32; off > 0; off >>= 1) {
      mn = fminf(mn, __shfl_xor(mn, off));
      mx = fmaxf(mx, __shfl_xor(mx, off));
    }
    if ((t & 63) == 0) { red[(t>>6)*2] = mn; red[(t>>6)*2+1] = mx; }
    __syncthreads();
    mn = red[0]; mx = red[1];
    #pragma unroll
    for (int w = 1; w < 16; ++w) { mn = fminf(mn, red[w*2]); mx = fmaxf(mx, red[w*2+1]); }
    const float step = (mx - mn) * 0.25f;
    const float e1 = mn + step, e2 = mn + 2.f*step, e3 = mn + 3.f*step;
    if (t < 256) {
      float sc = ox[(b*SS + t)*2 + 1];
      asg[t] = (sc >= e1) + (sc >= e2) + (sc >= e3);
    }
    __syncthreads();
    if (t < EE) {
      int c = 0;
      for (int s2 = 0; s2 < SS; ++s2) c += (asg[s2] == t);
      cnt[t] = c;
    }
    __syncthreads();
    int* SPw  = (int*)ws + WS_SPI;
    int* OFFw = SPw + BB*SS;
    if (t < EE) {
      int off = 0;
      for (int i = 0; i < t; ++i) off += cnt[i];
      OFFw[b*EE + t] = off;
      int kp = off;
      for (int s2 = 0; s2 < SS; ++s2) if (asg[s2] == t) SPw[b*SS + (kp++)] = s2;
    }
    if (t < 128) {
      int ee = t >> 5, d = t & 31;
      float m = 0.f;
      for (int i = 0; i < DD; ++i) m += sb[i];
      m *= (1.0f/DD);
      float var = 0.f;
      for (int i = 0; i < DD; ++i) { float df = sb[i]-m; var += df*df; }
      var *= (1.0f/DD);
      float rs = rsqrtf(var + 1e-5f);
      z0[ee*DD + d] = (sb[d]-m)*rs*g1[ee*DD+d] + bb1[ee*DD+d];
    }
    __syncthreads();
    if (b == 0 && t < 128) {
      int ee = t >> 5, d = t & 31;
      float k0 = 0.f, v0 = 0.f;
      for (int i = 0; i < DD; ++i) {
        float zz = z0[ee*DD + i];
        k0 += zz * Wk[ee*DD*DD + i*DD + d];
        v0 += zz * Wv[ee*DD*DD + i*DD + d];
      }
      ws[WS_K0 + ee*DD + d] = k0;
      ws[WS_V0 + ee*DD + d] = v0;
    }
  } else {
    unsigned* img = (unsigned*)ws + WS_WT;
    const int base_u = (blockIdx.x - 272)*4096;
    #pragma unroll
    for (int i = 0; i < 4; ++i) {
      int u = base_u + i*1024 + t;
      unsigned val;
      if (u < 6144) {                    // Wq/Wk/Wv T
        int mat = u >> 11, r = u & 2047;
        int row = r >> 4, ip = r & 15;
        int e = row >> 5, q = row & 31;
        int d = (q & 3)*8 + (q >> 2);
        const float* Wm = (mat == 0) ? Wq : (mat == 1) ? Wk : Wv;
        const float* src = Wm + e*1024 + d;
        val = pkh2(src[ip*64], src[ip*64 + 32]);
      } else {
        int v = u - 6144;
        if (v < 2048) {                  // WoT
          int row = v >> 4, ip = v & 15;
          int e = row >> 5, q = row & 31;
          int d = (q & 3)*8 + (q >> 2);
          const float* src = Wo + e*1024 + d;
          val = pkh2(src[ip*64], src[ip*64 + 32]);
        } else if (v < 6144) {           // W1T
          int r = v - 2048;
          int row = r >> 4, ip = r & 15;
          int e = row >> 6, q = row & 63;
          int j = (q & 3)*16 + (q >> 2);
          const float* src = W1 + e*2048 + j;
          val = pkh2(src[ip*128], src[ip*128 + 64]);
        } else {                         // W2T (two planes)
          int r = v - 6144;
          int a = r >> 11, rr = r & 2047;
          int row = rr >> 4, ip = rr & 15;
          int e = row >> 5, q = row & 31;
          int d = (q & 3)*8 + (q >> 2);
          int jp = a*16 + ip;
          const float* src = W2 + e*2048 + d;
          val = pkh2(src[2*jp*32], src[(2*jp+1)*32]);
        }
      }
      img[u] = val;
    }
  }
}

// ---------------------------------------------------------------------------
// Kernel 2: fused LN1+qkv+attn+Wo+LN2+FFN. Grid (b,n)=256 x 1024 thr.
// Only TWO barriers (stage drain, kv staged); all cross-thread exchange after
// attention via quad-lane DPP broadcasts (the 4 head-threads of a position
// are one DPP quad). LDS 96 KB: kv [0,8192) | wT [8192,14336) | wl [14336,..).
// ---------------------------------------------------------------------------
__launch_bounds__(1024, 4)
__global__ void fused_kernel(const float* __restrict__ ws,
    const float* __restrict__ g1, const float* __restrict__ bb1,
    const float* __restrict__ sW, const float* __restrict__ sb,
    const float* __restrict__ g2, const float* __restrict__ bb2,
    const float* __restrict__ b1, const float* __restrict__ b2,
    float* __restrict__ out) {
  const int blk = blockIdx.x;
  const int n = blk & 15;
  const int b = blk >> 4;
  const int t = threadIdx.x;
  const int p = t >> 2;         // sorted position 0..255
  const int hh = t & 3;
  __shared__ unsigned lds[24576];
  unsigned* wT = lds + 8192;
  unsigned* wl = lds + 14336;

  // async-stage both weight images (16384 uints = 64 x 1KB chunks, 4/wave)
  {
    const unsigned* img = (const unsigned*)ws + WS_WT;
    const int wv = t >> 6;
    const int ln = t & 63;
    #pragma unroll
    for (int i = 0; i < 4; ++i) {
      const int ch = wv*4 + i;
      __builtin_amdgcn_global_load_lds(
          (const __attribute__((address_space(1))) unsigned*)(img + ch*256 + ln*4),
          (__attribute__((address_space(3))) unsigned*)(wT + ch*256 + ln*4),
          16, 0, 0);
    }
  }

  const int* SP  = (const int*)ws + WS_SPI;
  const int* OFF = SP + BB*SS;
  const int o1 = OFF[b*4+1], o2v = OFF[b*4+2], o3 = OFF[b*4+3];
  const int e = (p >= o1) + (p >= o2v) + (p >= o3);
  const int beg = (e==0) ? 0  : ((e==1) ? o1 : ((e==2) ? o2v : o3));
  const int end = (e==0) ? o1 : ((e==1) ? o2v : ((e==2) ? o3 : SS));
  const int s = SP[b*SS + p];
  const float xv = ws[WS_XNS + (b*SS + s)*NCH + n];

  // LN1 (replicated x4 per position; cheap)
  float h[DD];
  #pragma unroll
  for (int d = 0; d < DD; ++d) h[d] = xv * sW[d] + sb[d];
  float m = 0.f;
  #pragma unroll
  for (int d = 0; d < DD; ++d) m += h[d];
  m *= (1.0f/DD);
  float var = 0.f;
  #pragma unroll
  for (int d = 0; d < DD; ++d) { float df = h[d]-m; var += df*df; }
  var *= (1.0f/DD);
  float rs = rsqrtf(var + 1e-5f);
  unsigned zp[16];
  #pragma unroll
  for (int ip = 0; ip < 16; ++ip) {
    float za = (h[2*ip]  -m)*rs*g1[e*DD+2*ip]   + bb1[e*DD+2*ip];
    float zb = (h[2*ip+1]-m)*rs*g1[e*DD+2*ip+1] + bb1[e*DD+2*ip+1];
    zp[ip] = pkh2(za, zb);
  }
  __syncthreads();   // barrier 1: weight images staged (vmcnt drained)

  // qkv for this (p, hh) slice via fdot2
  float q[DH], kk[DH], vv[DH];
  #pragma unroll
  for (int dd = 0; dd < DH; ++dd) {
    const int row16 = (e*32 + dd*4 + hh)*16;    // permuted rows: hh low bits
    const uint4* rq = (const uint4*)&wT[row16];
    const uint4* rk = (const uint4*)&wT[2048 + row16];
    const uint4* rv = (const uint4*)&wT[4096 + row16];
    float aq = 0.f, ak = 0.f, av = 0.f;
    #pragma unroll
    for (int g4 = 0; g4 < 4; ++g4) {
      uint4 wq4 = rq[g4], wk4 = rk[g4], wv4 = rv[g4];
      aq = fd2(zp[4*g4+0], wq4.x, aq); aq = fd2(zp[4*g4+1], wq4.y, aq);
      aq = fd2(zp[4*g4+2], wq4.z, aq); aq = fd2(zp[4*g4+3], wq4.w, aq);
      ak = fd2(zp[4*g4+0], wk4.x, ak); ak = fd2(zp[4*g4+1], wk4.y, ak);
      ak = fd2(zp[4*g4+2], wk4.z, ak); ak = fd2(zp[4*g4+3], wk4.w, ak);
      av = fd2(zp[4*g4+0], wv4.x, av); av = fd2(zp[4*g4+1], wv4.y, av);
      av = fd2(zp[4*g4+2], wv4.z, av); av = fd2(zp[4*g4+3], wv4.w, av);
    }
    q[dd] = aq * PRE; kk[dd] = ak; vv[dd] = av;
  }
  // write k/v to LDS (f16 packed)
  *(uint4*)&lds[p*32 + hh*8]     = make_uint4(pkh2(kk[0],kk[1]), pkh2(kk[2],kk[3]),
                                              pkh2(kk[4],kk[5]), pkh2(kk[6],kk[7]));
  *(uint4*)&lds[p*32 + hh*8 + 4] = make_uint4(pkh2(vv[0],vv[1]), pkh2(vv[2],vv[3]),
                                              pkh2(vv[4],vv[5]), pkh2(vv[6],vv[7]));
  unsigned qp2[4];
  #pragma unroll
  for (int i = 0; i < 4; ++i) qp2[i] = pkh2(q[2*i], q[2*i+1]);
  float s0 = 0.f;
  #pragma unroll
  for (int d = 0; d < DH; ++d) s0 += q[d] * ws[WS_K0 + e*DD + hh*DH + d];
  __syncthreads();   // barrier 2: kv staged — LAST barrier

  // attention: o accumulated as packed f16 pairs (v_pk_fma_f16)
  float wsum = 0.f;
  __half2 o2[4];
  #pragma unroll
  for (int i = 0; i < 4; ++i) o2[i] = u2h2(0u);
  int jk = beg;
  for (; jk + 1 < end; jk += 2) {
    uint4 ku0 = *(const uint4*)&lds[jk*32 + hh*8];
    uint4 vu0 = *(const uint4*)&lds[jk*32 + hh*8 + 4];
    uint4 ku1 = *(const uint4*)&lds[(jk+1)*32 + hh*8];
    uint4 vu1 = *(const uint4*)&lds[(jk+1)*32 + hh*8 + 4];
    float a0 = 0.f, a1 = 0.f;
    a0 = fd2(qp2[0], ku0.x, a0); a0 = fd2(qp2[1], ku0.y, a0);
    a0 = fd2(qp2[2], ku0.z, a0); a0 = fd2(qp2[3], ku0.w, a0);
    a1 = fd2(qp2[0], ku1.x, a1); a1 = fd2(qp2[1], ku1.y, a1);
    a1 = fd2(qp2[2], ku1.z, a1); a1 = fd2(qp2[3], ku1.w, a1);
    float w0f = __builtin_amdgcn_exp2f(a0);
    float w1f = __builtin_amdgcn_exp2f(a1);
    wsum += w0f + w1f;
    __half2 w20 = u2h2(pkh2(w0f, w0f));
    __half2 w21 = u2h2(pkh2(w1f, w1f));
    o2[0] = __hfma2(w20, u2h2(vu0.x), o2[0]);
    o2[1] = __hfma2(w20, u2h2(vu0.y), o2[1]);
    o2[2] = __hfma2(w20, u2h2(vu0.z), o2[2]);
    o2[3] = __hfma2(w20, u2h2(vu0.w), o2[3]);
    o2[0] = __hfma2(w21, u2h2(vu1.x), o2[0]);
    o2[1] = __hfma2(w21, u2h2(vu1.y), o2[1]);
    o2[2] = __hfma2(w21, u2h2(vu1.z), o2[2]);
    o2[3] = __hfma2(w21, u2h2(vu1.w), o2[3]);
  }
  if (jk < end) {
    uint4 ku = *(const uint4*)&lds[jk*32 + hh*8];
    uint4 vu = *(const uint4*)&lds[jk*32 + hh*8 + 4];
    float a = 0.f;
    a = fd2(qp2[0], ku.x, a); a = fd2(qp2[1], ku.y, a);
    a = fd2(qp2[2], ku.z, a); a = fd2(qp2[3], ku.w, a);
    float wf = __builtin_amdgcn_exp2f(a);
    wsum += wf;
    __half2 w2 = u2h2(pkh2(wf, wf));
    o2[0] = __hfma2(w2, u2h2(vu.x), o2[0]);
    o2[1] = __hfma2(w2, u2h2(vu.y), o2[1]);
    o2[2] = __hfma2(w2, u2h2(vu.z), o2[2]);
    o2[3] = __hfma2(w2, u2h2(vu.w), o2[3]);
  }
  // off-expert keys: constant score s0, constant value v0
  float o[DH];
  #pragma unroll
  for (int i = 0; i < 4; ++i) {
    o[2*i]   = __low2float(o2[i]);
    o[2*i+1] = __high2float(o2[i]);
  }
  const int nmis = SS - (end - beg);
  float w0 = (float)nmis * __builtin_amdgcn_exp2f(s0);
  wsum += w0;
  #pragma unroll
  for (int d = 0; d < DH; ++d) o[d] += w0 * ws[WS_V0 + e*DD + hh*DH + d];
  float inv = 1.0f / wsum;
  #pragma unroll
  for (int d = 0; d < DH; ++d) o[d] *= inv;

  // ---- o gather via DPP quad broadcast (no barrier, no LDS) ----
  unsigned oq[4];
  #pragma unroll
  for (int j = 0; j < 4; ++j) oq[j] = pkh2(o[2*j], o[2*j+1]);
  unsigned ovp[16];
  #pragma unroll
  for (int j = 0; j < 4; ++j) {
    ovp[j]    = qdpp<0x00>(oq[j]);
    ovp[4+j]  = qdpp<0x55>(oq[j]);
    ovp[8+j]  = qdpp<0xAA>(oq[j]);
    ovp[12+j] = qdpp<0xFF>(oq[j]);
  }

  // Wo + residual: acc[dd] = h2 at dim hh*8+dd
  float acc[DH];
  #pragma unroll
  for (int dd = 0; dd < DH; ++dd) {
    int d = hh*DH + dd;
    const uint4* row = (const uint4*)&wl[(e*32 + dd*4 + hh)*16];
    float a = xv * sW[d] + sb[d];
    #pragma unroll
    for (int g4 = 0; g4 < 4; ++g4) {
      uint4 w4 = row[g4];
      a = fd2(ovp[4*g4+0], w4.x, a); a = fd2(ovp[4*g4+1], w4.y, a);
      a = fd2(ovp[4*g4+2], w4.z, a); a = fd2(ovp[4*g4+3], w4.w, a);
    }
    acc[dd] = a;
  }

  // ---- LN2 via quad-sum DPP reductions ----
  float ssum = 0.f;
  #pragma unroll
  for (int dd = 0; dd < DH; ++dd) ssum += acc[dd];
  ssum += qdppf<0xB1>(ssum);
  ssum += qdppf<0x4E>(ssum);
  float m2 = ssum * (1.0f/DD);
  float vs = 0.f;
  #pragma unroll
  for (int dd = 0; dd < DH; ++dd) { float df = acc[dd]-m2; vs += df*df; }
  vs += qdppf<0xB1>(vs);
  vs += qdppf<0x4E>(vs);
  float rs2 = rsqrtf(vs * (1.0f/DD) + 1e-5f);
  unsigned zq[4];
  #pragma unroll
  for (int j = 0; j < 4; ++j) {
    int d = hh*DH + 2*j;
    float za = (acc[2*j]  -m2)*rs2*g2[e*DD+d]   + bb2[e*DD+d];
    float zb = (acc[2*j+1]-m2)*rs2*g2[e*DD+d+1] + bb2[e*DD+d+1];
    zq[j] = pkh2(za, zb);
  }
  unsigned zp2[16];
  #pragma unroll
  for (int j = 0; j < 4; ++j) {
    zp2[j]    = qdpp<0x00>(zq[j]);
    zp2[4+j]  = qdpp<0x55>(zq[j]);
    zp2[8+j]  = qdpp<0xAA>(zq[j]);
    zp2[12+j] = qdpp<0xFF>(zq[j]);
  }

  // FFN1: f[hh*16 .. +16)
  float f[16];
  #pragma unroll
  for (int jj = 0; jj < 16; ++jj) {
    const uint4* row = (const uint4*)&wl[2048 + (e*64 + jj*4 + hh)*16];
    float a = b1[e*DFFN + hh*16 + jj];
    #pragma unroll
    for (int g4 = 0; g4 < 4; ++g4) {
      uint4 w4 = row[g4];
      a = fd2(zp2[4*g4+0], w4.x, a); a = fd2(zp2[4*g4+1], w4.y, a);
      a = fd2(zp2[4*g4+2], w4.z, a); a = fd2(zp2[4*g4+3], w4.w, a);
    }
    f[jj] = fmaxf(a, 0.0f);
  }
  // ---- f gather via DPP quad broadcast ----
  unsigned fq[8];
  #pragma unroll
  for (int j = 0; j < 8; ++j) fq[j] = pkh2(f[2*j], f[2*j+1]);
  unsigned fu[32];
  #pragma unroll
  for (int j = 0; j < 8; ++j) {
    fu[j]    = qdpp<0x00>(fq[j]);
    fu[8+j]  = qdpp<0x55>(fq[j]);
    fu[16+j] = qdpp<0xAA>(fq[j]);
    fu[24+j] = qdpp<0xFF>(fq[j]);
  }

  // FFN2 + residual + b2
  float acc2[DH];
  #pragma unroll
  for (int dd = 0; dd < DH; ++dd) {
    int d = hh*DH + dd;
    const int row16 = (e*32 + dd*4 + hh)*16;
    float a = acc[dd] + b2[e*DD + d];
    #pragma unroll
    for (int g4 = 0; g4 < 8; ++g4) {
      const int plane = (g4 >> 2);
      uint4 w4 = *(const uint4*)&wl[6144 + plane*2048 + row16 + 4*(g4 & 3)];
      a = fd2(fu[4*g4+0], w4.x, a); a = fd2(fu[4*g4+1], w4.y, a);
      a = fd2(fu[4*g4+2], w4.z, a); a = fd2(fu[4*g4+3], w4.w, a);
    }
    acc2[dd] = a;
  }
  float* op = out + ((size_t)((b*SS + s)*NCH + n))*DD + hh*DH;
  *(float4*)(op)     = make_float4(acc2[0], acc2[1], acc2[2], acc2[3]);
  *(float4*)(op + 4) = make_float4(acc2[4], acc2[5], acc2[6], acc2[7]);
}

// ---------------------------------------------------------------------------
extern "C" void kernel_launch(void* const* d_in, const int* in_sizes, int n_in,
                              void* d_out, int out_size, void* d_ws, size_t ws_size,
                              hipStream_t stream) {
  (void)in_sizes; (void)n_in; (void)out_size; (void)ws_size;
  const float* x   = (const float*)d_in[0];
  const float* ox  = (const float*)d_in[1];
  const float* sW  = (const float*)d_in[2];
  const float* sb  = (const float*)d_in[3];
  const float* Wq  = (const float*)d_in[4];
  const float* Wk  = (const float*)d_in[5];
  const float* Wv  = (const float*)d_in[6];
  const float* Wo  = (const float*)d_in[7];
  const float* g1  = (const float*)d_in[8];
  const float* b1n = (const float*)d_in[9];
  const float* g2  = (const float*)d_in[10];
  const float* b2n = (const float*)d_in[11];
  const float* W1  = (const float*)d_in[12];
  const float* bf1 = (const float*)d_in[13];
  const float* W2  = (const float*)d_in[14];
  const float* bf2 = (const float*)d_in[15];
  float* out = (float*)d_out;
  float* ws  = (float*)d_ws;

  decomp_prep_kernel<<<276, 1024, 0, stream>>>(x, ox, sb, g1, b1n,
                                               Wq, Wk, Wv, Wo, W1, W2, ws);
  fused_kernel<<<BB*NCH, 1024, 0, stream>>>(ws, g1, b1n, sW, sb, g2, b2n,
                                            bf1, bf2, out);
}